// Round 15
// baseline (447.950 us; speedup 1.0000x reference)
//
#include <hip/hip_runtime.h>
#include <math.h>

typedef unsigned short u16;
typedef __attribute__((ext_vector_type(8))) short bf16x8;
typedef __attribute__((ext_vector_type(4))) float f32x4;

// padded row space: per (s,b) tokens padded to NPAD; M' = 36864 = 288*128
#define MP 36864
#define OUTOFF0 25692160ull

#define DEV __device__ __forceinline__
#define AS1 __attribute__((address_space(1)))
#define AS3 __attribute__((address_space(3)))

DEV u16 f2bf(float x) {
  union { float f; unsigned u; } v; v.f = x;
  unsigned r = v.u + 0x7fffu + ((v.u >> 16) & 1u);
  return (u16)(r >> 16);
}
DEV float bf2f(u16 x) {
  union { unsigned u; float f; } v; v.u = ((unsigned)x) << 16;
  return v.f;
}

struct alignas(8) u16x4s { u16 x, y, z, w; };
struct alignas(16) U16x8 { u16 d[8]; };

DEV int rs_s(int row)   { return (row >= 25600) + (row >= 33792) + (row >= 35840); }
DEV int selPB(int s)    { return s == 0 ? 0 : s == 1 ? 25600 : s == 2 ? 33792 : 35840; }
DEV int selNPAD(int s)  { return s == 0 ? 3200 : s == 1 ? 1024 : s == 2 ? 256 : 128; }
DEV int selN(int s)     { return s == 0 ? 3137 : s == 1 ? 785 : s == 2 ? 197 : 50; }
DEV int selH(int s)     { return s == 0 ? 56 : s == 1 ? 28 : s == 2 ? 14 : 7; }
DEV int selRO(int s)    { return s == 0 ? 0 : s == 1 ? 25096 : s == 2 ? 31376 : 32952; }
DEV size_t selKPB(int s){ return s == 0 ? 0ull : s == 1 ? 6553600ull : s == 2 ? 8650752ull : 9175040ull; }
DEV size_t selVPB(int s){ return s == 0 ? 0ull : s == 1 ? 7340032ull : s == 2 ? 11010048ull : 12845056ull; }
DEV int selNC(int s)    { return s == 0 ? 32 : s == 1 ? 8 : s == 2 ? 2 : 1; }
DEV int selNCB(int s)   { return s == 0 ? 0 : s == 1 ? 2048 : s == 2 ? 2560 : 2688; }

DEV void sbn(int row, int s, int& b, int& n) {
  int l = row - selPB(s);
  if (s == 0)      { b = l / 3200; n = l - b * 3200; }
  else if (s == 1) { b = l >> 10; n = l & 1023; }
  else if (s == 2) { b = l >> 8;  n = l & 255; }
  else             { b = l >> 7;  n = l & 127; }
}

DEV int xcd_swizzle(int orig, int nblk) {
  int q = nblk >> 3, r = nblk & 7;
  int xcd = orig & 7, lin = orig >> 3;
  return (xcd < r ? xcd * (q + 1) : r * (q + 1) + (xcd - r) * q) + lin;
}

// ---------------- small prep kernels ----------------
__global__ void cvt_all(const float* __restrict__ qkv_w, const float* __restrict__ proj_w,
                        const float* __restrict__ fc1_w, const float* __restrict__ fc2_w,
                        u16* __restrict__ WQ, u16* __restrict__ WP,
                        u16* __restrict__ W1, u16* __restrict__ W2) {
  int i = blockIdx.x * 256 + threadIdx.x;
  if (i < 786432) WQ[i] = f2bf(qkv_w[i]);
  else if (i < 1048576) WP[i - 786432] = f2bf(proj_w[i - 786432]);
  else if (i < 1310720) W1[i - 1048576] = f2bf(fc1_w[i - 1048576]);
  else if (i < 1572864) W2[i - 1310720] = f2bf(fc2_w[i - 1310720]);
}

__global__ void tpw_cpe(const float* __restrict__ src, float* __restrict__ dst) {
  int i = blockIdx.y;
  int e = blockIdx.x * 256 + threadIdx.x;
  if (e < 2304) {
    int c = e / 9, k = e % 9;
    dst[i * 2304 + k * 256 + c] = src[i * 2304 + c * 9 + k];
  }
}

__global__ void copy_f4(const float4* __restrict__ src, float4* __restrict__ dst, int n4) {
  for (int i = blockIdx.x * blockDim.x + threadIdx.x; i < n4; i += gridDim.x * blockDim.x)
    dst[i] = src[i];
}

// ---------------- fused CPE + LN1 (wave per padded row) ----------------
__global__ void cpe_ln_all(const float* __restrict__ x2, const float* __restrict__ x3,
                           const float* __restrict__ x4, const float* __restrict__ x5,
                           const float* __restrict__ WT, const float* __restrict__ cpe_b,
                           const float* __restrict__ n1g, const float* __restrict__ n1b,
                           float* __restrict__ XI, u16* __restrict__ T1) {
  int wid = threadIdx.x >> 6, lane = threadIdx.x & 63;
  int row = blockIdx.x * 4 + wid;
  if (row >= MP) return;
  int s = rs_s(row);
  int b, n; sbn(row, s, b, n);
  int N = selN(s), H = selH(s);
  int c4 = lane * 4;
  float4 v = make_float4(0.f, 0.f, 0.f, 0.f);
  if (n < N) {
    const float* x = s == 0 ? x2 : s == 1 ? x3 : s == 2 ? x4 : x5;
    v = *(const float4*)(x + ((size_t)b * N + n) * 256 + c4);
    if (n > 0) {
      int p = n - 1, h0 = p / H, w0 = p % H;
      float4 acc = *(const float4*)(cpe_b + s * 256 + c4);
      const float* wT = WT + s * 2304;
      #pragma unroll
      for (int kh = 0; kh < 3; ++kh) {
        int hh = h0 + kh - 1;
        if (hh < 0 || hh >= H) continue;
        #pragma unroll
        for (int kw = 0; kw < 3; ++kw) {
          int ww = w0 + kw - 1;
          if (ww < 0 || ww >= H) continue;
          float4 t = *(const float4*)(x + ((size_t)b * N + 1 + hh * H + ww) * 256 + c4);
          float4 wv = *(const float4*)(wT + (kh * 3 + kw) * 256 + c4);
          acc.x += t.x * wv.x; acc.y += t.y * wv.y;
          acc.z += t.z * wv.z; acc.w += t.w * wv.w;
        }
      }
      v.x += acc.x; v.y += acc.y; v.z += acc.z; v.w += acc.w;
    }
  }
  *(float4*)(XI + (size_t)row * 256 + c4) = v;
  float sm = v.x + v.y + v.z + v.w;
  #pragma unroll
  for (int off = 32; off; off >>= 1) sm += __shfl_down(sm, off);
  sm = __shfl(sm, 0);
  float mu = sm * (1.0f / 256.0f);
  float dx = v.x - mu, dy = v.y - mu, dz = v.z - mu, dw = v.w - mu;
  float q = dx * dx + dy * dy + dz * dz + dw * dw;
  #pragma unroll
  for (int off = 32; off; off >>= 1) q += __shfl_down(q, off);
  q = __shfl(q, 0);
  float rs = rsqrtf(q * (1.0f / 256.0f) + 1e-5f);
  float4 gg = *(const float4*)(n1g + s * 256 + c4);
  float4 bb = *(const float4*)(n1b + s * 256 + c4);
  u16x4s o;
  o.x = f2bf(dx * rs * gg.x + bb.x);
  o.y = f2bf(dy * rs * gg.y + bb.y);
  o.z = f2bf(dz * rs * gg.z + bb.z);
  o.w = f2bf(dw * rs * gg.w + bb.w);
  *(u16x4s*)(T1 + (size_t)row * 256 + c4) = o;
}

// ---------------- GEMM: BK=32, 3-buffer depth-2 pipeline, counted vmcnt, setprio ----------------
DEV void stage32(const u16* __restrict__ A, const u16* __restrict__ W,
                 u16* dst, int bm, int bn, int K, int k0) {
  int t = threadIdx.x, wv = t >> 6;
  u16* aD = dst;
  u16* bD = dst + 4096;
  #pragma unroll
  for (int iss = 0; iss < 2; ++iss) {
    int sI = iss * 256 + t;
    int row = sI >> 2, g = sI & 3;
    int gel = ((g ^ (row & 3)) << 3);
    __builtin_amdgcn_global_load_lds(
        (const AS1 void*)(A + (size_t)(bm + row) * K + k0 + gel),
        (AS3 void*)(aD + (size_t)(iss * 256 + wv * 64) * 8), 16, 0, 0);
    __builtin_amdgcn_global_load_lds(
        (const AS1 void*)(W + (size_t)(bn + row) * K + k0 + gel),
        (AS3 void*)(bD + (size_t)(iss * 256 + wv * 64) * 8), 16, 0, 0);
  }
}

DEV void mainloop(const u16* __restrict__ A, const u16* __restrict__ W, int K,
                  int bm, int bn, u16* lds, f32x4 (&acc)[4][4]) {
  int t = threadIdx.x, lane = t & 63, wv = t >> 6;
  int wr = wv >> 1, wc = wv & 1;
  const int nt = K >> 5;
  stage32(A, W, lds, bm, bn, K, 0);
  stage32(A, W, lds + 8192, bm, bn, K, 32);
  int buf = 0;
  for (int tt = 0; tt < nt; ++tt) {
    if (tt + 1 < nt) asm volatile("s_waitcnt vmcnt(4)" ::: "memory");
    else             asm volatile("s_waitcnt vmcnt(0)" ::: "memory");
    __builtin_amdgcn_s_barrier();
    asm volatile("" ::: "memory");
    if (tt + 2 < nt) {
      int nb = buf + 2; if (nb >= 3) nb -= 3;
      stage32(A, W, lds + nb * 8192, bm, bn, K, (tt + 2) << 5);
    }
    const u16* aS = lds + buf * 8192;
    const u16* bS = aS + 4096;
    bf16x8 af[4], bfr[4];
    #pragma unroll
    for (int m = 0; m < 4; ++m) {
      int row = wr * 64 + m * 16 + (lane & 15);
      int sg = (lane >> 4) ^ (row & 3);
      af[m] = *(const bf16x8*)(aS + row * 32 + sg * 8);
    }
    #pragma unroll
    for (int n = 0; n < 4; ++n) {
      int row = wc * 64 + n * 16 + (lane & 15);
      int sg = (lane >> 4) ^ (row & 3);
      bfr[n] = *(const bf16x8*)(bS + row * 32 + sg * 8);
    }
    __builtin_amdgcn_s_setprio(1);
    #pragma unroll
    for (int m = 0; m < 4; ++m)
      #pragma unroll
      for (int n = 0; n < 4; ++n)
        acc[m][n] = __builtin_amdgcn_mfma_f32_16x16x32_bf16(af[m], bfr[n], acc[m][n], 0, 0, 0);
    __builtin_amdgcn_s_setprio(0);
    buf += 1; if (buf >= 3) buf -= 3;
  }
}

DEV void epi_dump(const f32x4 (&acc)[4][4], int pass, float* eps) {
  int t = threadIdx.x, lane = t & 63, wv = t >> 6;
  int wr = wv >> 1, wc = wv & 1;
  if (wr != (pass >> 1)) return;
  #pragma unroll
  for (int mh = 0; mh < 2; ++mh) {
    int m = (pass & 1) * 2 + mh;
    #pragma unroll
    for (int n = 0; n < 4; ++n) {
      int col = wc * 64 + n * 16 + (lane & 15);
      #pragma unroll
      for (int rg = 0; rg < 4; ++rg)
        eps[(mh * 16 + ((lane >> 4) << 2) + rg) * 132 + col] = acc[m][n][rg];
    }
  }
}

template <bool GELU, bool BF16>
DEV void epi_rowmajor(const float* eps, int pass, void* outp, const float* bias,
                      int bm, int bn, int Nout) {
  int t = threadIdx.x;
  int lr = t >> 3, cb = (t & 7) * 4;
  int gr = bm + pass * 32 + lr;
  #pragma unroll
  for (int j = 0; j < 4; ++j) {
    int col = cb + j * 32;
    float4 f = *(const float4*)(eps + lr * 132 + col);
    int gc = bn + col;
    if (bias) {
      float4 bv = *(const float4*)(bias + gc);
      f.x += bv.x; f.y += bv.y; f.z += bv.z; f.w += bv.w;
    }
    if (GELU) {
      f.x /= (1.0f + __expf(-1.702f * f.x));
      f.y /= (1.0f + __expf(-1.702f * f.y));
      f.z /= (1.0f + __expf(-1.702f * f.z));
      f.w /= (1.0f + __expf(-1.702f * f.w));
    }
    if (BF16) {
      u16x4s p;
      p.x = f2bf(f.x); p.y = f2bf(f.y); p.z = f2bf(f.z); p.w = f2bf(f.w);
      *(u16x4s*)((u16*)outp + (size_t)gr * Nout + gc) = p;
    } else {
      *(float4*)((float*)outp + (size_t)gr * Nout + gc) = f;
    }
  }
}

// ---------------- standard GEMM (fc1) ----------------
template <bool GELU, bool BF16>
__launch_bounds__(256, 4)
__global__ void gemm_std(const u16* __restrict__ A, const u16* __restrict__ W,
                         const float* __restrict__ bias, void* __restrict__ outp,
                         int K, int Nout, int nnt) {
  __shared__ __align__(16) u16 lds[24576];
  int wg = xcd_swizzle(blockIdx.x, gridDim.x);
  int bm = (wg / nnt) << 7, bn = (wg % nnt) << 7;
  f32x4 acc[4][4] = {};
  mainloop(A, W, K, bm, bn, lds, acc);
  float* eps = (float*)lds;
  #pragma unroll
  for (int pass = 0; pass < 4; ++pass) {
    __syncthreads();
    epi_dump(acc, pass, eps);
    __syncthreads();
    epi_rowmajor<GELU, BF16>(eps, pass, outp, bias, bm, bn, Nout);
  }
}

// ---------------- qkv GEMM: q row-major bf16; k,v planar-transposed ----------------
__launch_bounds__(256, 4)
__global__ void qkv_gemm(const u16* __restrict__ A, const u16* __restrict__ WQ,
                         u16* __restrict__ Q16, u16* __restrict__ KP,
                         u16* __restrict__ VP) {
  __shared__ __align__(16) u16 lds[24576];
  int wg = xcd_swizzle(blockIdx.x, gridDim.x);
  int mt = wg / 6, ct = wg % 6;
  int bm = mt << 7, bn = ct << 7;
  int s = rs_s(bm);
  f32x4 acc[4][4] = {};
  mainloop(A, WQ + (size_t)s * 196608, 256, bm, bn, lds, acc);
  float* eps = (float*)lds;
  int b, nb; sbn(bm, s, b, nb);
  int NPAD = selNPAD(s);
  #pragma unroll
  for (int pass = 0; pass < 4; ++pass) {
    __syncthreads();
    epi_dump(acc, pass, eps);
    __syncthreads();
    if (ct < 2) {
      epi_rowmajor<false, true>(eps, pass, Q16, nullptr, bm, bn, 256);
    } else {
      int t = threadIdx.x;
      int c = t >> 1, half = t & 1;
      bool isK = (ct < 4);
      int cg = bn - (isK ? 256 : 512) + c;
      int n0 = nb + pass * 32 + half * 16;
      float vals[16];
      #pragma unroll
      for (int r = 0; r < 16; ++r) vals[r] = eps[(half * 16 + r) * 132 + c];
      U16x8 p0, p1;
      #pragma unroll
      for (int e = 0; e < 8; ++e) { p0.d[e] = f2bf(vals[e]); p1.d[e] = f2bf(vals[8 + e]); }
      u16* pbase = (isK ? KP : VP) + selKPB(s) + (size_t)(b * 256 + cg) * NPAD + n0;
      *(U16x8*)pbase = p0;
      *(U16x8*)(pbase + 8) = p1;
    }
  }
}

// ---------------- proj GEMM ----------------
__launch_bounds__(256, 4)
__global__ void proj_gemm(const u16* __restrict__ A, const u16* __restrict__ WP,
                          const float* __restrict__ proj_b, float* __restrict__ CC) {
  __shared__ __align__(16) u16 lds[24576];
  int wg = xcd_swizzle(blockIdx.x, gridDim.x);
  int bm = (wg >> 1) << 7, bn = (wg & 1) << 7;
  int s = rs_s(bm);
  f32x4 acc[4][4] = {};
  mainloop(A, WP + (size_t)s * 65536, 256, bm, bn, lds, acc);
  float* eps = (float*)lds;
  #pragma unroll
  for (int pass = 0; pass < 4; ++pass) {
    __syncthreads();
    epi_dump(acc, pass, eps);
    __syncthreads();
    epi_rowmajor<false, false>(eps, pass, CC, proj_b + s * 256, bm, bn, 256);
  }
}

// ---------------- fc2 GEMM: +bias +XI residual, remapped f32 out ----------------
__launch_bounds__(256, 4)
__global__ void fc2_gemm(const u16* __restrict__ A, const u16* __restrict__ W2,
                         const float* __restrict__ fc2_b, const float* __restrict__ XI,
                         float* __restrict__ out) {
  __shared__ __align__(16) u16 lds[24576];
  int wg = xcd_swizzle(blockIdx.x, gridDim.x);
  int bm = (wg >> 1) << 7, bn = (wg & 1) << 7;
  f32x4 acc[4][4] = {};
  mainloop(A, W2, 1024, bm, bn, lds, acc);
  float* eps = (float*)lds;
  int s = rs_s(bm);
  int b, nb; sbn(bm, s, b, nb);
  int N = selN(s), RO = selRO(s);
  #pragma unroll
  for (int pass = 0; pass < 4; ++pass) {
    __syncthreads();
    epi_dump(acc, pass, eps);
    __syncthreads();
    int t = threadIdx.x;
    int lr = t >> 3, cb = (t & 7) * 4;
    int n = nb + pass * 32 + lr;
    if (n >= N) continue;
    int prow = bm + pass * 32 + lr;
    size_t orow = (size_t)RO + (size_t)b * N + n;
    #pragma unroll
    for (int j = 0; j < 4; ++j) {
      int col = cb + j * 32;
      float4 f = *(const float4*)(eps + lr * 132 + col);
      int gc = bn + col;
      float4 bv = *(const float4*)(fc2_b + gc);
      float4 rv = *(const float4*)(XI + (size_t)prow * 256 + gc);
      f.x += bv.x + rv.x; f.y += bv.y + rv.y;
      f.z += bv.z + rv.z; f.w += bv.w + rv.w;
      *(float4*)(out + OUTOFF0 + orow * 256 + gc) = f;
    }
  }
}

// ---------------- padded V-image from planar VP (coalesced) ----------------
__global__ void vimg_fill(const u16* __restrict__ VP, u16* __restrict__ VPI) {
  int plane = blockIdx.x;
  int s = plane >> 11;
  int pc = plane & 2047;
  int H = selH(s), NPAD = selNPAD(s);
  const u16* vp = VP + selKPB(s) + (size_t)pc * NPAD;
  u16* vi = VPI + selVPB(s) + (size_t)pc * (H * 64);
  int tot = H * 64;
  for (int e = threadIdx.x; e < tot; e += 256) {
    int h = e >> 6, w = e & 63;
    vi[e] = (w < H) ? vp[1 + h * H + w] : (u16)0;
  }
}

// ---------------- k softmax stats ----------------
__global__ void ksm_all(const u16* __restrict__ KP, float* __restrict__ mx,
                        float* __restrict__ se) {
  int s = blockIdx.z, b = blockIdx.y;
  int N = selN(s), NPAD = selNPAD(s);
  int wv = threadIdx.x >> 6, lane = threadIdx.x & 63;
  int cg = blockIdx.x * 4 + wv;
  const u16* kp = KP + selKPB(s) + (size_t)(b * 256 + cg) * NPAD;
  float m = -1e30f, sm = 0.f;
  for (int n = lane; n < N; n += 64) {
    float v = bf2f(kp[n]);
    float nm = fmaxf(m, v);
    sm = sm * __expf(m - nm) + __expf(v - nm);
    m = nm;
  }
  #pragma unroll
  for (int off = 1; off < 64; off <<= 1) {
    float mo = __shfl_xor(m, off), so = __shfl_xor(sm, off);
    float nm = fmaxf(m, mo);
    sm = sm * __expf(m - nm) + so * __expf(mo - nm);
    m = nm;
  }
  if (lane == 0) { mx[s * 2048 + b * 256 + cg] = m; se[s * 2048 + b * 256 + cg] = sm; }
}

// ---------------- kv partials ----------------
__launch_bounds__(1024)
__global__ void kv_partial_all(const u16* __restrict__ KP, const u16* __restrict__ VP,
                               const float* __restrict__ mx, float* __restrict__ part) {
  __shared__ float kl[32][65];
  __shared__ float vl[32][65];
  int blk = blockIdx.x;
  int s = (blk >= selNCB(1)) + (blk >= selNCB(2)) + (blk >= selNCB(3));
  int local = blk - selNCB(s);
  int NC = selNC(s);
  int chunk = local % NC;
  int bh = local / NC;
  int b = bh >> 3, h = bh & 7;
  int N = selN(s), NPAD = selNPAD(s);
  int chunkrows = (N + NC - 1) / NC;
  const u16* kpb = KP + selKPB(s);
  const u16* vpb = VP + selKPB(s);
  int t = threadIdx.x;
  int i = t >> 5, j = t & 31;
  float acc = 0.f;
  int n0s = chunk * chunkrows, n1s = min(N, n0s + chunkrows);
  for (int n0 = n0s; n0 < n1s; n0 += 64) {
    #pragma unroll
    for (int e = t; e < 2048; e += 1024) {
      int c = e >> 6, nn = e & 63;
      int n = n0 + nn;
      bool ok = (n < n1s);
      kl[c][nn] = ok ? bf2f(kpb[(size_t)(b * 256 + h * 32 + c) * NPAD + n]) : -1e30f;
      vl[c][nn] = ok ? bf2f(vpb[(size_t)(b * 256 + h * 32 + c) * NPAD + n]) : 0.f;
    }
    __syncthreads();
    #pragma unroll
    for (int e = t; e < 2048; e += 1024) {
      int c = e >> 6, nn = e & 63;
      kl[c][nn] = __expf(kl[c][nn] - mx[s * 2048 + b * 256 + h * 32 + c]);
    }
    __syncthreads();
    #pragma unroll
    for (int nn = 0; nn < 64; ++nn) acc += kl[i][nn] * vl[j][nn];
    __syncthreads();
  }
  part[(size_t)blk * 1024 + t] = acc;
}

// kv table in bf16: KVH[s][b][h][k][j]
__global__ void kv_reduce_all(const float* __restrict__ part, const float* __restrict__ se,
                              u16* __restrict__ kvh) {
  int bh = blockIdx.x, s = blockIdx.y;
  int NC = selNC(s), base = selNCB(s);
  int t = threadIdx.x;
  int i = t >> 5;
  int b = bh >> 3, h = bh & 7;
  float sm = 0.f;
  for (int c = 0; c < NC; ++c) sm += part[(size_t)(base + bh * NC + c) * 1024 + t];
  kvh[(size_t)s * 65536 + bh * 1024 + t] = f2bf(sm / se[s * 2048 + b * 256 + h * 32 + i]);
}

// ---------------- CRPE depthwise conv on padded planes ----------------
template <int KS, int C0>
__global__ void crpe_all(const u16* __restrict__ VPI, const float* __restrict__ w,
                         const float* __restrict__ bias, u16* __restrict__ CVPI, int CS) {
  constexpr int pad = KS / 2;
  int z = blockIdx.z;
  int s = (z >= 2) + (z >= 3) + (z >= 4);
  int sub = z - (s == 0 ? 0 : s + 1);
  int RS = (s == 0) ? 2 : 1;
  int H = selH(s);
  int c = blockIdx.x, b = blockIdx.y;
  int G = (H + 7) >> 3;
  int hpb = (H + RS - 1) / RS;
  int h0b = sub * hpb;
  int h1b = min(H, h0b + hpb);
  size_t plane = selVPB(s) + (size_t)(b * 256 + C0 + c) * (size_t)(H * 64);
  const u16* vp = VPI + plane;
  u16* op = CVPI + plane;
  float wreg[KS * KS];
  #pragma unroll
  for (int e = 0; e < KS * KS; ++e) wreg[e] = w[(s * CS + c) * KS * KS + e];
  float bb = bias[s * CS + c];
  int ntask = (h1b - h0b) * G;
  for (int task = threadIdx.x; task < ntask; task += 256) {
    int g = task % G;
    int h = h0b + task / G;
    int w0 = g << 3;
    float o[8];
    #pragma unroll
    for (int e = 0; e < 8; ++e) o[e] = bb;
    #pragma unroll
    for (int kh = 0; kh < KS; ++kh) {
      int hh = h + kh - pad;
      if (hh < 0 || hh >= H) continue;
      const u16* rowp = vp + hh * 64;
      U16x8 ch0 = {}, ch1, ch2;
      if (w0 >= 8) ch0 = *(const U16x8*)(rowp + w0 - 8);
      ch1 = *(const U16x8*)(rowp + w0);
      ch2 = *(const U16x8*)(rowp + w0 + 8);
      float tv[24];
      #pragma unroll
      for (int j2 = 8 - pad; j2 <= 15 + pad; ++j2) {
        u16 raw = (j2 < 8) ? ch0.d[j2] : (j2 < 16 ? ch1.d[j2 - 8] : ch2.d[j2 - 16]);
        tv[j2] = bf2f(raw);
      }
      #pragma unroll
      for (int kw = 0; kw < KS; ++kw) {
        float wv = wreg[kh * KS + kw];
        #pragma unroll
        for (int e = 0; e < 8; ++e) o[e] += tv[8 + e + kw - pad] * wv;
      }
    }
    U16x8 pk;
    #pragma unroll
    for (int e = 0; e < 8; ++e) pk.d[e] = f2bf(o[e]);
    *(U16x8*)(op + h * 64 + w0) = pk;
  }
}

// ---------------- att v2: 32 tokens/block, bf16 LDS, kv column in registers ----------------
__launch_bounds__(256, 3)
__global__ void att_all(const u16* __restrict__ Q16, const u16* __restrict__ CVPI,
                        const u16* __restrict__ kvh, u16* __restrict__ attp) {
  int s = blockIdx.z, b = blockIdx.y;
  int N = selN(s), H = selH(s);
  int n0 = blockIdx.x * 32;
  if (n0 >= N) return;
  __shared__ u16 kvl[8192];
  __shared__ u16 ql[32][256];
  __shared__ u16 cl[32][256];
  int t = threadIdx.x;
  int hw64 = H * 64;
  size_t rowbase = (size_t)selPB(s) + (size_t)b * selNPAD(s);
  const u16* cvb = CVPI + selVPB(s);
  const u16* kvsrc = kvh + (size_t)s * 65536 + (size_t)b * 8192;
  for (int e = t; e < 1024; e += 256)
    *(U16x8*)(kvl + e * 8) = *(const U16x8*)(kvsrc + e * 8);
  for (int e = t; e < 1024; e += 256)
    *(U16x8*)(&ql[0][0] + e * 8) = *(const U16x8*)(Q16 + (rowbase + n0) * 256 + e * 8);
  for (int e = t; e < 8192; e += 256) {
    int c = e >> 5, nn = e & 31;
    int n = n0 + nn;
    u16 v = 0;
    if (n >= 1 && n < N) {
      int p = n - 1;
      v = cvb[(size_t)(b * 256 + c) * hw64 + (p / H) * 64 + (p % H)];
    }
    cl[nn][c] = v;
  }
  __syncthreads();
  int h = t >> 5, j = t & 31;
  float kvr[32];
  #pragma unroll
  for (int k = 0; k < 32; ++k) kvr[k] = bf2f(kvl[(h * 32 + k) * 32 + j]);
  for (int nn = 0; nn < 32; ++nn) {
    int n = n0 + nn;
    if (n >= N) break;
    float fa = 0.f;
    const U16x8* qp = (const U16x8*)(&ql[nn][h * 32]);
    #pragma unroll
    for (int seg = 0; seg < 4; ++seg) {
      U16x8 qq = qp[seg];
      #pragma unroll
      for (int e = 0; e < 8; ++e) fa += bf2f(qq.d[e]) * kvr[seg * 8 + e];
    }
    float v = 0.17677669529663687f * fa + bf2f(ql[nn][t]) * bf2f(cl[nn][t]);
    attp[(rowbase + n) * 256 + t] = f2bf(v);
  }
}

// ---------------- fused cross-scale combine + LN2 ----------------
DEV float4 bs4(const float* __restrict__ base, int Hs, int oh, int ow, int Hi, int c4) {
  float scale = (float)Hs / (float)Hi;
  float sy = (oh + 0.5f) * scale - 0.5f;
  float sx = (ow + 0.5f) * scale - 0.5f;
  float fy0 = floorf(sy), fx0 = floorf(sx);
  float fy = sy - fy0, fx = sx - fx0;
  int y0 = (int)fy0, x0 = (int)fx0;
  int y0c = min(max(y0, 0), Hs - 1), y1c = min(max(y0 + 1, 0), Hs - 1);
  int x0c = min(max(x0, 0), Hs - 1), x1c = min(max(x0 + 1, 0), Hs - 1);
  const float* ib = base + 256 + c4;
  float4 v00 = *(const float4*)(ib + (size_t)(y0c * Hs + x0c) * 256);
  float4 v01 = *(const float4*)(ib + (size_t)(y0c * Hs + x1c) * 256);
  float4 v10 = *(const float4*)(ib + (size_t)(y1c * Hs + x0c) * 256);
  float4 v11 = *(const float4*)(ib + (size_t)(y1c * Hs + x1c) * 256);
  float w00 = (1.f - fy) * (1.f - fx), w01 = (1.f - fy) * fx;
  float w10 = fy * (1.f - fx), w11 = fy * fx;
  float4 r;
  r.x = w00 * v00.x + w01 * v01.x + w10 * v10.x + w11 * v11.x;
  r.y = w00 * v00.y + w01 * v01.y + w10 * v10.y + w11 * v11.y;
  r.z = w00 * v00.z + w01 * v01.z + w10 * v10.z + w11 * v11.z;
  r.w = w00 * v00.w + w01 * v01.w + w10 * v10.w + w11 * v11.w;
  return r;
}

__global__ void combine_ln_all(float* __restrict__ XI, const float* __restrict__ CC,
                               const float* __restrict__ n2g, const float* __restrict__ n2b,
                               u16* __restrict__ T1) {
  int wid = threadIdx.x >> 6, lane = threadIdx.x & 63;
  int row = blockIdx.x * 4 + wid;
  if (row >= MP) return;
  int s = rs_s(row);
  int b, n; sbn(row, s, b, n);
  int N = selN(s), Hi = selH(s);
  int c4 = lane * 4;
  float4 v;
  if (n < N) {
    float4 add = *(const float4*)(CC + (size_t)row * 256 + c4);
    int sa = s == 0 ? 1 : s == 1 ? 2 : s == 2 ? 3 : 2;
    int sb_ = s == 0 ? 2 : 0;
    const float* baseA = CC + ((size_t)selPB(sa) + (size_t)b * selNPAD(sa)) * 256;
    const float* baseB = CC + ((size_t)selPB(sb_) + (size_t)b * selNPAD(sb_)) * 256;
    if (n == 0) {
      float4 a = *(const float4*)(baseA + c4);
      float4 bb2 = *(const float4*)(baseB + c4);
      add.x += a.x + bb2.x; add.y += a.y + bb2.y;
      add.z += a.z + bb2.z; add.w += a.w + bb2.w;
    } else {
      int p = n - 1, oh = p / Hi, ow = p % Hi;
      float4 a = bs4(baseA, selH(sa), oh, ow, Hi, c4);
      float4 bb2 = bs4(baseB, selH(sb_), oh, ow, Hi, c4);
      add.x += a.x + bb2.x; add.y += a.y + bb2.y;
      add.z += a.z + bb2.z; add.w += a.w + bb2.w;
    }
    float* xp = XI + (size_t)row * 256 + c4;
    v = *(const float4*)xp;
    v.x += add.x; v.y += add.y; v.z += add.z; v.w += add.w;
    *(float4*)xp = v;
  } else {
    v = make_float4(0.f, 0.f, 0.f, 0.f);
  }
  float sm = v.x + v.y + v.z + v.w;
  #pragma unroll
  for (int off = 32; off; off >>= 1) sm += __shfl_down(sm, off);
  sm = __shfl(sm, 0);
  float mu = sm * (1.0f / 256.0f);
  float dx = v.x - mu, dy = v.y - mu, dz = v.z - mu, dw = v.w - mu;
  float q = dx * dx + dy * dy + dz * dz + dw * dw;
  #pragma unroll
  for (int off = 32; off; off >>= 1) q += __shfl_down(q, off);
  q = __shfl(q, 0);
  float rs = rsqrtf(q * (1.0f / 256.0f) + 1e-5f);
  float4 gg = *(const float4*)(n2g + s * 256 + c4);
  float4 bb = *(const float4*)(n2b + s * 256 + c4);
  u16x4s o;
  o.x = f2bf(dx * rs * gg.x + bb.x);
  o.y = f2bf(dy * rs * gg.y + bb.y);
  o.z = f2bf(dz * rs * gg.z + bb.z);
  o.w = f2bf(dw * rs * gg.w + bb.w);
  *(u16x4s*)(T1 + (size_t)row * 256 + c4) = o;
}

// ---------------- host ----------------
extern "C" void kernel_launch(void* const* d_in, const int* in_sizes, int n_in,
                              void* d_out, int out_size, void* d_ws, size_t ws_size,
                              hipStream_t stream) {
  const float* x1 = (const float*)d_in[0];
  const float* x2 = (const float*)d_in[1];
  const float* x3 = (const float*)d_in[2];
  const float* x4 = (const float*)d_in[3];
  const float* x5 = (const float*)d_in[4];
  const float* cpe_w  = (const float*)d_in[5];
  const float* cpe_b  = (const float*)d_in[6];
  const float* n1_g   = (const float*)d_in[7];
  const float* n1_b   = (const float*)d_in[8];
  const float* qkv_w  = (const float*)d_in[9];
  const float* proj_w = (const float*)d_in[10];
  const float* proj_b = (const float*)d_in[11];
  const float* crpe_w3 = (const float*)d_in[12];
  const float* crpe_b3 = (const float*)d_in[13];
  const float* crpe_w5 = (const float*)d_in[14];
  const float* crpe_b5 = (const float*)d_in[15];
  const float* crpe_w7 = (const float*)d_in[16];
  const float* crpe_b7 = (const float*)d_in[17];
  const float* n2_g   = (const float*)d_in[18];
  const float* n2_b   = (const float*)d_in[19];
  const float* fc1_w  = (const float*)d_in[20];
  const float* fc1_b  = (const float*)d_in[21];
  const float* fc2_w  = (const float*)d_in[22];
  const float* fc2_b  = (const float*)d_in[23];

  float* ws = (float*)d_ws;
  float* XI   = ws;
  float* CC   = XI + 9437184;
  u16*   T1   = (u16*)(CC + 9437184);
  float* REG  = (float*)(T1 + 9437184);
  u16*   Q16  = (u16*)REG;
  u16*   KP   = Q16 + 9437184;
  u16*   VP   = KP + 9437184;
  u16*   VPI  = VP + 9437184;
  u16*   CVPI = VPI + 13762560;
  float* PRT  = (float*)CVPI;
  u16*   T2   = (u16*)REG;
  float* MX   = (float*)(CVPI + 13762560);
  float* SE   = MX + 8192;
  u16*   KVH  = (u16*)(SE + 8192);
  u16*   WQ   = KVH + 262144;
  u16*   WP   = WQ + 786432;
  u16*   W1   = WP + 262144;
  u16*   W2   = W1 + 262144;
  float* WT   = (float*)(W2 + 262144);

  float* out = (float*)d_out;

  cvt_all<<<6144, 256, 0, stream>>>(qkv_w, proj_w, fc1_w, fc2_w, WQ, WP, W1, W2);
  tpw_cpe<<<dim3(9, 4), 256, 0, stream>>>(cpe_w, WT);

  copy_f4<<<8192, 256, 0, stream>>>((const float4*)x1, (float4*)out, 25692160 / 4);

  // phase 1a: fused CPE + LN1
  cpe_ln_all<<<MP / 4, 256, 0, stream>>>(x2, x3, x4, x5, WT, cpe_b, n1_g, n1_b, XI, T1);

  // phase 1b: qkv GEMM (q row-major, k/v planar)
  qkv_gemm<<<288 * 6, 256, 0, stream>>>(T1, WQ, Q16, KP, VP);
  vimg_fill<<<8192, 256, 0, stream>>>(VP, VPI);

  // phase 1c: attention mid-section
  ksm_all<<<dim3(64, 8, 4), 256, 0, stream>>>(KP, MX, SE);
  kv_partial_all<<<2752, 1024, 0, stream>>>(KP, VP, MX, PRT);
  kv_reduce_all<<<dim3(64, 4), 1024, 0, stream>>>(PRT, SE, KVH);
  crpe_all<3, 0><<<dim3(64, 8, 5), 256, 0, stream>>>(VPI, crpe_w3, crpe_b3, CVPI, 64);
  crpe_all<5, 64><<<dim3(96, 8, 5), 256, 0, stream>>>(VPI, crpe_w5, crpe_b5, CVPI, 96);
  crpe_all<7, 160><<<dim3(96, 8, 5), 256, 0, stream>>>(VPI, crpe_w7, crpe_b7, CVPI, 96);
  att_all<<<dim3(99, 8, 4), 256, 0, stream>>>(Q16, CVPI, KVH, T1);

  // phase 1d: proj GEMM (f32 -> CC)
  proj_gemm<<<288 * 2, 256, 0, stream>>>(T1, WP, proj_b, CC);

  // phase 2: fused combine + LN2
  combine_ln_all<<<MP / 4, 256, 0, stream>>>(XI, CC, n2_g, n2_b, T1);

  // phase 3: MLP
  gemm_std<true, true><<<288 * 8, 256, 0, stream>>>(T1, W1, fc1_b, (void*)T2, 256, 1024, 8);
  fc2_gemm<<<288 * 2, 256, 0, stream>>>(T2, W2, fc2_b, XI, out);
}

// Round 16
// 426.946 us; speedup vs baseline: 1.0492x; 1.0492x over previous
//
#include <hip/hip_runtime.h>
#include <math.h>

typedef unsigned short u16;
typedef __attribute__((ext_vector_type(8))) short bf16x8;
typedef __attribute__((ext_vector_type(4))) float f32x4;

// padded row space: per (s,b) tokens padded to NPAD; M' = 36864 = 288*128
#define MP 36864
#define OUTOFF0 25692160ull

#define DEV __device__ __forceinline__
#define AS1 __attribute__((address_space(1)))
#define AS3 __attribute__((address_space(3)))

DEV u16 f2bf(float x) {
  union { float f; unsigned u; } v; v.f = x;
  unsigned r = v.u + 0x7fffu + ((v.u >> 16) & 1u);
  return (u16)(r >> 16);
}
DEV float bf2f(u16 x) {
  union { unsigned u; float f; } v; v.u = ((unsigned)x) << 16;
  return v.f;
}

struct alignas(8) u16x4s { u16 x, y, z, w; };
struct alignas(16) U16x8 { u16 d[8]; };

DEV int rs_s(int row)   { return (row >= 25600) + (row >= 33792) + (row >= 35840); }
DEV int selPB(int s)    { return s == 0 ? 0 : s == 1 ? 25600 : s == 2 ? 33792 : 35840; }
DEV int selNPAD(int s)  { return s == 0 ? 3200 : s == 1 ? 1024 : s == 2 ? 256 : 128; }
DEV int selN(int s)     { return s == 0 ? 3137 : s == 1 ? 785 : s == 2 ? 197 : 50; }
DEV int selH(int s)     { return s == 0 ? 56 : s == 1 ? 28 : s == 2 ? 14 : 7; }
DEV int selRO(int s)    { return s == 0 ? 0 : s == 1 ? 25096 : s == 2 ? 31376 : 32952; }
DEV size_t selKPB(int s){ return s == 0 ? 0ull : s == 1 ? 6553600ull : s == 2 ? 8650752ull : 9175040ull; }
DEV size_t selVPB(int s){ return s == 0 ? 0ull : s == 1 ? 7340032ull : s == 2 ? 11010048ull : 12845056ull; }
DEV int selNC(int s)    { return s == 0 ? 32 : s == 1 ? 8 : s == 2 ? 2 : 1; }
DEV int selNCB(int s)   { return s == 0 ? 0 : s == 1 ? 2048 : s == 2 ? 2560 : 2688; }

DEV void sbn(int row, int s, int& b, int& n) {
  int l = row - selPB(s);
  if (s == 0)      { b = l / 3200; n = l - b * 3200; }
  else if (s == 1) { b = l >> 10; n = l & 1023; }
  else if (s == 2) { b = l >> 8;  n = l & 255; }
  else             { b = l >> 7;  n = l & 127; }
}

DEV int xcd_swizzle(int orig, int nblk) {
  int q = nblk >> 3, r = nblk & 7;
  int xcd = orig & 7, lin = orig >> 3;
  return (xcd < r ? xcd * (q + 1) : r * (q + 1) + (xcd - r) * q) + lin;
}

// ---------------- small prep kernels ----------------
__global__ void cvt_all(const float* __restrict__ qkv_w, const float* __restrict__ proj_w,
                        const float* __restrict__ fc1_w, const float* __restrict__ fc2_w,
                        u16* __restrict__ WQ, u16* __restrict__ WP,
                        u16* __restrict__ W1, u16* __restrict__ W2) {
  int i = blockIdx.x * 256 + threadIdx.x;
  if (i < 786432) WQ[i] = f2bf(qkv_w[i]);
  else if (i < 1048576) WP[i - 786432] = f2bf(proj_w[i - 786432]);
  else if (i < 1310720) W1[i - 1048576] = f2bf(fc1_w[i - 1048576]);
  else if (i < 1572864) W2[i - 1310720] = f2bf(fc2_w[i - 1310720]);
}

__global__ void tpw_cpe(const float* __restrict__ src, float* __restrict__ dst) {
  int i = blockIdx.y;
  int e = blockIdx.x * 256 + threadIdx.x;
  if (e < 2304) {
    int c = e / 9, k = e % 9;
    dst[i * 2304 + k * 256 + c] = src[i * 2304 + c * 9 + k];
  }
}

__global__ void copy_f4(const float4* __restrict__ src, float4* __restrict__ dst, int n4) {
  for (int i = blockIdx.x * blockDim.x + threadIdx.x; i < n4; i += gridDim.x * blockDim.x)
    dst[i] = src[i];
}

// ---------------- fused CPE + LN1 (wave per padded row) ----------------
__global__ void cpe_ln_all(const float* __restrict__ x2, const float* __restrict__ x3,
                           const float* __restrict__ x4, const float* __restrict__ x5,
                           const float* __restrict__ WT, const float* __restrict__ cpe_b,
                           const float* __restrict__ n1g, const float* __restrict__ n1b,
                           float* __restrict__ XI, u16* __restrict__ T1) {
  int wid = threadIdx.x >> 6, lane = threadIdx.x & 63;
  int row = blockIdx.x * 4 + wid;
  if (row >= MP) return;
  int s = rs_s(row);
  int b, n; sbn(row, s, b, n);
  int N = selN(s), H = selH(s);
  int c4 = lane * 4;
  float4 v = make_float4(0.f, 0.f, 0.f, 0.f);
  if (n < N) {
    const float* x = s == 0 ? x2 : s == 1 ? x3 : s == 2 ? x4 : x5;
    v = *(const float4*)(x + ((size_t)b * N + n) * 256 + c4);
    if (n > 0) {
      int p = n - 1, h0 = p / H, w0 = p % H;
      float4 acc = *(const float4*)(cpe_b + s * 256 + c4);
      const float* wT = WT + s * 2304;
      #pragma unroll
      for (int kh = 0; kh < 3; ++kh) {
        int hh = h0 + kh - 1;
        if (hh < 0 || hh >= H) continue;
        #pragma unroll
        for (int kw = 0; kw < 3; ++kw) {
          int ww = w0 + kw - 1;
          if (ww < 0 || ww >= H) continue;
          float4 t = *(const float4*)(x + ((size_t)b * N + 1 + hh * H + ww) * 256 + c4);
          float4 wv = *(const float4*)(wT + (kh * 3 + kw) * 256 + c4);
          acc.x += t.x * wv.x; acc.y += t.y * wv.y;
          acc.z += t.z * wv.z; acc.w += t.w * wv.w;
        }
      }
      v.x += acc.x; v.y += acc.y; v.z += acc.z; v.w += acc.w;
    }
  }
  *(float4*)(XI + (size_t)row * 256 + c4) = v;
  float sm = v.x + v.y + v.z + v.w;
  #pragma unroll
  for (int off = 32; off; off >>= 1) sm += __shfl_down(sm, off);
  sm = __shfl(sm, 0);
  float mu = sm * (1.0f / 256.0f);
  float dx = v.x - mu, dy = v.y - mu, dz = v.z - mu, dw = v.w - mu;
  float q = dx * dx + dy * dy + dz * dz + dw * dw;
  #pragma unroll
  for (int off = 32; off; off >>= 1) q += __shfl_down(q, off);
  q = __shfl(q, 0);
  float rs = rsqrtf(q * (1.0f / 256.0f) + 1e-5f);
  float4 gg = *(const float4*)(n1g + s * 256 + c4);
  float4 bb = *(const float4*)(n1b + s * 256 + c4);
  u16x4s o;
  o.x = f2bf(dx * rs * gg.x + bb.x);
  o.y = f2bf(dy * rs * gg.y + bb.y);
  o.z = f2bf(dz * rs * gg.z + bb.z);
  o.w = f2bf(dw * rs * gg.w + bb.w);
  *(u16x4s*)(T1 + (size_t)row * 256 + c4) = o;
}

// ---------------- GEMM: BK=32, 3-buffer depth-2 pipeline, counted vmcnt ----------------
DEV void stage32(const u16* __restrict__ A, const u16* __restrict__ W,
                 u16* dst, int bm, int bn, int K, int k0) {
  int t = threadIdx.x, wv = t >> 6;
  u16* aD = dst;
  u16* bD = dst + 4096;
  #pragma unroll
  for (int iss = 0; iss < 2; ++iss) {
    int sI = iss * 256 + t;
    int row = sI >> 2, g = sI & 3;
    int gel = ((g ^ (row & 3)) << 3);
    __builtin_amdgcn_global_load_lds(
        (const AS1 void*)(A + (size_t)(bm + row) * K + k0 + gel),
        (AS3 void*)(aD + (size_t)(iss * 256 + wv * 64) * 8), 16, 0, 0);
    __builtin_amdgcn_global_load_lds(
        (const AS1 void*)(W + (size_t)(bn + row) * K + k0 + gel),
        (AS3 void*)(bD + (size_t)(iss * 256 + wv * 64) * 8), 16, 0, 0);
  }
}

DEV void mainloop(const u16* __restrict__ A, const u16* __restrict__ W, int K,
                  int bm, int bn, u16* lds, f32x4 (&acc)[4][4]) {
  int t = threadIdx.x, lane = t & 63, wv = t >> 6;
  int wr = wv >> 1, wc = wv & 1;
  const int nt = K >> 5;
  stage32(A, W, lds, bm, bn, K, 0);
  stage32(A, W, lds + 8192, bm, bn, K, 32);
  int buf = 0;
  for (int tt = 0; tt < nt; ++tt) {
    if (tt + 1 < nt) asm volatile("s_waitcnt vmcnt(4)" ::: "memory");
    else             asm volatile("s_waitcnt vmcnt(0)" ::: "memory");
    __builtin_amdgcn_s_barrier();
    asm volatile("" ::: "memory");
    if (tt + 2 < nt) {
      int nb = buf + 2; if (nb >= 3) nb -= 3;
      stage32(A, W, lds + nb * 8192, bm, bn, K, (tt + 2) << 5);
    }
    const u16* aS = lds + buf * 8192;
    const u16* bS = aS + 4096;
    bf16x8 af[4], bfr[4];
    #pragma unroll
    for (int m = 0; m < 4; ++m) {
      int row = wr * 64 + m * 16 + (lane & 15);
      int sg = (lane >> 4) ^ (row & 3);
      af[m] = *(const bf16x8*)(aS + row * 32 + sg * 8);
    }
    #pragma unroll
    for (int n = 0; n < 4; ++n) {
      int row = wc * 64 + n * 16 + (lane & 15);
      int sg = (lane >> 4) ^ (row & 3);
      bfr[n] = *(const bf16x8*)(bS + row * 32 + sg * 8);
    }
    #pragma unroll
    for (int m = 0; m < 4; ++m)
      #pragma unroll
      for (int n = 0; n < 4; ++n)
        acc[m][n] = __builtin_amdgcn_mfma_f32_16x16x32_bf16(af[m], bfr[n], acc[m][n], 0, 0, 0);
    buf += 1; if (buf >= 3) buf -= 3;
  }
}

DEV void epi_dump(const f32x4 (&acc)[4][4], int pass, float* eps) {
  int t = threadIdx.x, lane = t & 63, wv = t >> 6;
  int wr = wv >> 1, wc = wv & 1;
  if (wr != (pass >> 1)) return;
  #pragma unroll
  for (int mh = 0; mh < 2; ++mh) {
    int m = (pass & 1) * 2 + mh;
    #pragma unroll
    for (int n = 0; n < 4; ++n) {
      int col = wc * 64 + n * 16 + (lane & 15);
      #pragma unroll
      for (int rg = 0; rg < 4; ++rg)
        eps[(mh * 16 + ((lane >> 4) << 2) + rg) * 132 + col] = acc[m][n][rg];
    }
  }
}

template <bool GELU, bool BF16>
DEV void epi_rowmajor(const float* eps, int pass, void* outp, const float* bias,
                      int bm, int bn, int Nout) {
  int t = threadIdx.x;
  int lr = t >> 3, cb = (t & 7) * 4;
  int gr = bm + pass * 32 + lr;
  #pragma unroll
  for (int j = 0; j < 4; ++j) {
    int col = cb + j * 32;
    float4 f = *(const float4*)(eps + lr * 132 + col);
    int gc = bn + col;
    if (bias) {
      float4 bv = *(const float4*)(bias + gc);
      f.x += bv.x; f.y += bv.y; f.z += bv.z; f.w += bv.w;
    }
    if (GELU) {
      f.x /= (1.0f + __expf(-1.702f * f.x));
      f.y /= (1.0f + __expf(-1.702f * f.y));
      f.z /= (1.0f + __expf(-1.702f * f.z));
      f.w /= (1.0f + __expf(-1.702f * f.w));
    }
    if (BF16) {
      u16x4s p;
      p.x = f2bf(f.x); p.y = f2bf(f.y); p.z = f2bf(f.z); p.w = f2bf(f.w);
      *(u16x4s*)((u16*)outp + (size_t)gr * Nout + gc) = p;
    } else {
      *(float4*)((float*)outp + (size_t)gr * Nout + gc) = f;
    }
  }
}

// ---------------- standard GEMM (fc1) ----------------
template <bool GELU, bool BF16>
__launch_bounds__(256, 3)
__global__ void gemm_std(const u16* __restrict__ A, const u16* __restrict__ W,
                         const float* __restrict__ bias, void* __restrict__ outp,
                         int K, int Nout, int nnt) {
  __shared__ __align__(16) u16 lds[24576];
  int wg = xcd_swizzle(blockIdx.x, gridDim.x);
  int bm = (wg / nnt) << 7, bn = (wg % nnt) << 7;
  f32x4 acc[4][4] = {};
  mainloop(A, W, K, bm, bn, lds, acc);
  float* eps = (float*)lds;
  #pragma unroll
  for (int pass = 0; pass < 4; ++pass) {
    __syncthreads();
    epi_dump(acc, pass, eps);
    __syncthreads();
    epi_rowmajor<GELU, BF16>(eps, pass, outp, bias, bm, bn, Nout);
  }
}

// ---------------- qkv GEMM: q row-major bf16; k,v planar-transposed ----------------
__launch_bounds__(256, 3)
__global__ void qkv_gemm(const u16* __restrict__ A, const u16* __restrict__ WQ,
                         u16* __restrict__ Q16, u16* __restrict__ KP,
                         u16* __restrict__ VP) {
  __shared__ __align__(16) u16 lds[24576];
  int wg = xcd_swizzle(blockIdx.x, gridDim.x);
  int mt = wg / 6, ct = wg % 6;
  int bm = mt << 7, bn = ct << 7;
  int s = rs_s(bm);
  f32x4 acc[4][4] = {};
  mainloop(A, WQ + (size_t)s * 196608, 256, bm, bn, lds, acc);
  float* eps = (float*)lds;
  int b, nb; sbn(bm, s, b, nb);
  int NPAD = selNPAD(s);
  #pragma unroll
  for (int pass = 0; pass < 4; ++pass) {
    __syncthreads();
    epi_dump(acc, pass, eps);
    __syncthreads();
    if (ct < 2) {
      epi_rowmajor<false, true>(eps, pass, Q16, nullptr, bm, bn, 256);
    } else {
      int t = threadIdx.x;
      int c = t >> 1, half = t & 1;
      bool isK = (ct < 4);
      int cg = bn - (isK ? 256 : 512) + c;
      int n0 = nb + pass * 32 + half * 16;
      float vals[16];
      #pragma unroll
      for (int r = 0; r < 16; ++r) vals[r] = eps[(half * 16 + r) * 132 + c];
      U16x8 p0, p1;
      #pragma unroll
      for (int e = 0; e < 8; ++e) { p0.d[e] = f2bf(vals[e]); p1.d[e] = f2bf(vals[8 + e]); }
      u16* pbase = (isK ? KP : VP) + selKPB(s) + (size_t)(b * 256 + cg) * NPAD + n0;
      *(U16x8*)pbase = p0;
      *(U16x8*)(pbase + 8) = p1;
    }
  }
}

// ---------------- proj GEMM (bf16 out into CC16) ----------------
__launch_bounds__(256, 3)
__global__ void proj_gemm(const u16* __restrict__ A, const u16* __restrict__ WP,
                          const float* __restrict__ proj_b, u16* __restrict__ CC16) {
  __shared__ __align__(16) u16 lds[24576];
  int wg = xcd_swizzle(blockIdx.x, gridDim.x);
  int bm = (wg >> 1) << 7, bn = (wg & 1) << 7;
  int s = rs_s(bm);
  f32x4 acc[4][4] = {};
  mainloop(A, WP + (size_t)s * 65536, 256, bm, bn, lds, acc);
  float* eps = (float*)lds;
  #pragma unroll
  for (int pass = 0; pass < 4; ++pass) {
    __syncthreads();
    epi_dump(acc, pass, eps);
    __syncthreads();
    epi_rowmajor<false, true>(eps, pass, CC16, proj_b + s * 256, bm, bn, 256);
  }
}

// ---------------- fc2 GEMM: +bias +XI residual, remapped f32 out ----------------
__launch_bounds__(256, 3)
__global__ void fc2_gemm(const u16* __restrict__ A, const u16* __restrict__ W2,
                         const float* __restrict__ fc2_b, const float* __restrict__ XI,
                         float* __restrict__ out) {
  __shared__ __align__(16) u16 lds[24576];
  int wg = xcd_swizzle(blockIdx.x, gridDim.x);
  int bm = (wg >> 1) << 7, bn = (wg & 1) << 7;
  f32x4 acc[4][4] = {};
  mainloop(A, W2, 1024, bm, bn, lds, acc);
  float* eps = (float*)lds;
  int s = rs_s(bm);
  int b, nb; sbn(bm, s, b, nb);
  int N = selN(s), RO = selRO(s);
  #pragma unroll
  for (int pass = 0; pass < 4; ++pass) {
    __syncthreads();
    epi_dump(acc, pass, eps);
    __syncthreads();
    int t = threadIdx.x;
    int lr = t >> 3, cb = (t & 7) * 4;
    int n = nb + pass * 32 + lr;
    if (n >= N) continue;
    int prow = bm + pass * 32 + lr;
    size_t orow = (size_t)RO + (size_t)b * N + n;
    #pragma unroll
    for (int j = 0; j < 4; ++j) {
      int col = cb + j * 32;
      float4 f = *(const float4*)(eps + lr * 132 + col);
      int gc = bn + col;
      float4 bv = *(const float4*)(fc2_b + gc);
      float4 rv = *(const float4*)(XI + (size_t)prow * 256 + gc);
      f.x += bv.x + rv.x; f.y += bv.y + rv.y;
      f.z += bv.z + rv.z; f.w += bv.w + rv.w;
      *(float4*)(out + OUTOFF0 + orow * 256 + gc) = f;
    }
  }
}

// ---------------- padded V-image from planar VP (coalesced) ----------------
__global__ void vimg_fill(const u16* __restrict__ VP, u16* __restrict__ VPI) {
  int plane = blockIdx.x;
  int s = plane >> 11;
  int pc = plane & 2047;
  int H = selH(s), NPAD = selNPAD(s);
  const u16* vp = VP + selKPB(s) + (size_t)pc * NPAD;
  u16* vi = VPI + selVPB(s) + (size_t)pc * (H * 64);
  int tot = H * 64;
  for (int e = threadIdx.x; e < tot; e += 256) {
    int h = e >> 6, w = e & 63;
    vi[e] = (w < H) ? vp[1 + h * H + w] : (u16)0;
  }
}

// ---------------- k softmax stats ----------------
__global__ void ksm_all(const u16* __restrict__ KP, float* __restrict__ mx,
                        float* __restrict__ se) {
  int s = blockIdx.z, b = blockIdx.y;
  int N = selN(s), NPAD = selNPAD(s);
  int wv = threadIdx.x >> 6, lane = threadIdx.x & 63;
  int cg = blockIdx.x * 4 + wv;
  const u16* kp = KP + selKPB(s) + (size_t)(b * 256 + cg) * NPAD;
  float m = -1e30f, sm = 0.f;
  for (int n = lane; n < N; n += 64) {
    float v = bf2f(kp[n]);
    float nm = fmaxf(m, v);
    sm = sm * __expf(m - nm) + __expf(v - nm);
    m = nm;
  }
  #pragma unroll
  for (int off = 1; off < 64; off <<= 1) {
    float mo = __shfl_xor(m, off), so = __shfl_xor(sm, off);
    float nm = fmaxf(m, mo);
    sm = sm * __expf(m - nm) + so * __expf(mo - nm);
    m = nm;
  }
  if (lane == 0) { mx[s * 2048 + b * 256 + cg] = m; se[s * 2048 + b * 256 + cg] = sm; }
}

// ---------------- kv partials ----------------
__launch_bounds__(1024)
__global__ void kv_partial_all(const u16* __restrict__ KP, const u16* __restrict__ VP,
                               const float* __restrict__ mx, float* __restrict__ part) {
  __shared__ float kl[32][65];
  __shared__ float vl[32][65];
  int blk = blockIdx.x;
  int s = (blk >= selNCB(1)) + (blk >= selNCB(2)) + (blk >= selNCB(3));
  int local = blk - selNCB(s);
  int NC = selNC(s);
  int chunk = local % NC;
  int bh = local / NC;
  int b = bh >> 3, h = bh & 7;
  int N = selN(s), NPAD = selNPAD(s);
  int chunkrows = (N + NC - 1) / NC;
  const u16* kpb = KP + selKPB(s);
  const u16* vpb = VP + selKPB(s);
  int t = threadIdx.x;
  int i = t >> 5, j = t & 31;
  float acc = 0.f;
  int n0s = chunk * chunkrows, n1s = min(N, n0s + chunkrows);
  for (int n0 = n0s; n0 < n1s; n0 += 64) {
    #pragma unroll
    for (int e = t; e < 2048; e += 1024) {
      int c = e >> 6, nn = e & 63;
      int n = n0 + nn;
      bool ok = (n < n1s);
      kl[c][nn] = ok ? bf2f(kpb[(size_t)(b * 256 + h * 32 + c) * NPAD + n]) : -1e30f;
      vl[c][nn] = ok ? bf2f(vpb[(size_t)(b * 256 + h * 32 + c) * NPAD + n]) : 0.f;
    }
    __syncthreads();
    #pragma unroll
    for (int e = t; e < 2048; e += 1024) {
      int c = e >> 6, nn = e & 63;
      kl[c][nn] = __expf(kl[c][nn] - mx[s * 2048 + b * 256 + h * 32 + c]);
    }
    __syncthreads();
    #pragma unroll
    for (int nn = 0; nn < 64; ++nn) acc += kl[i][nn] * vl[j][nn];
    __syncthreads();
  }
  part[(size_t)blk * 1024 + t] = acc;
}

// kv table in bf16: KVH[s][b][h][k][j]
__global__ void kv_reduce_all(const float* __restrict__ part, const float* __restrict__ se,
                              u16* __restrict__ kvh) {
  int bh = blockIdx.x, s = blockIdx.y;
  int NC = selNC(s), base = selNCB(s);
  int t = threadIdx.x;
  int i = t >> 5;
  int b = bh >> 3, h = bh & 7;
  float sm = 0.f;
  for (int c = 0; c < NC; ++c) sm += part[(size_t)(base + bh * NC + c) * 1024 + t];
  kvh[(size_t)s * 65536 + bh * 1024 + t] = f2bf(sm / se[s * 2048 + b * 256 + h * 32 + i]);
}

// ---------------- CRPE depthwise conv on padded planes ----------------
template <int KS, int C0>
__global__ void crpe_all(const u16* __restrict__ VPI, const float* __restrict__ w,
                         const float* __restrict__ bias, u16* __restrict__ CVPI, int CS) {
  constexpr int pad = KS / 2;
  int z = blockIdx.z;
  int s = (z >= 2) + (z >= 3) + (z >= 4);
  int sub = z - (s == 0 ? 0 : s + 1);
  int RS = (s == 0) ? 2 : 1;
  int H = selH(s);
  int c = blockIdx.x, b = blockIdx.y;
  int G = (H + 7) >> 3;
  int hpb = (H + RS - 1) / RS;
  int h0b = sub * hpb;
  int h1b = min(H, h0b + hpb);
  size_t plane = selVPB(s) + (size_t)(b * 256 + C0 + c) * (size_t)(H * 64);
  const u16* vp = VPI + plane;
  u16* op = CVPI + plane;
  float wreg[KS * KS];
  #pragma unroll
  for (int e = 0; e < KS * KS; ++e) wreg[e] = w[(s * CS + c) * KS * KS + e];
  float bb = bias[s * CS + c];
  int ntask = (h1b - h0b) * G;
  for (int task = threadIdx.x; task < ntask; task += 256) {
    int g = task % G;
    int h = h0b + task / G;
    int w0 = g << 3;
    float o[8];
    #pragma unroll
    for (int e = 0; e < 8; ++e) o[e] = bb;
    #pragma unroll
    for (int kh = 0; kh < KS; ++kh) {
      int hh = h + kh - pad;
      if (hh < 0 || hh >= H) continue;
      const u16* rowp = vp + hh * 64;
      U16x8 ch0 = {}, ch1, ch2;
      if (w0 >= 8) ch0 = *(const U16x8*)(rowp + w0 - 8);
      ch1 = *(const U16x8*)(rowp + w0);
      ch2 = *(const U16x8*)(rowp + w0 + 8);
      float tv[24];
      #pragma unroll
      for (int j2 = 8 - pad; j2 <= 15 + pad; ++j2) {
        u16 raw = (j2 < 8) ? ch0.d[j2] : (j2 < 16 ? ch1.d[j2 - 8] : ch2.d[j2 - 16]);
        tv[j2] = bf2f(raw);
      }
      #pragma unroll
      for (int kw = 0; kw < KS; ++kw) {
        float wv = wreg[kh * KS + kw];
        #pragma unroll
        for (int e = 0; e < 8; ++e) o[e] += tv[8 + e + kw - pad] * wv;
      }
    }
    U16x8 pk;
    #pragma unroll
    for (int e = 0; e < 8; ++e) pk.d[e] = f2bf(o[e]);
    *(U16x8*)(op + h * 64 + w0) = pk;
  }
}

// ---------------- att v2: 32 tokens/block, bf16 LDS, kv column in registers ----------------
__launch_bounds__(256, 3)
__global__ void att_all(const u16* __restrict__ Q16, const u16* __restrict__ CVPI,
                        const u16* __restrict__ kvh, u16* __restrict__ attp) {
  int s = blockIdx.z, b = blockIdx.y;
  int N = selN(s), H = selH(s);
  int n0 = blockIdx.x * 32;
  if (n0 >= N) return;
  __shared__ u16 kvl[8192];
  __shared__ u16 ql[32][256];
  __shared__ u16 cl[32][256];
  int t = threadIdx.x;
  int hw64 = H * 64;
  size_t rowbase = (size_t)selPB(s) + (size_t)b * selNPAD(s);
  const u16* cvb = CVPI + selVPB(s);
  const u16* kvsrc = kvh + (size_t)s * 65536 + (size_t)b * 8192;
  for (int e = t; e < 1024; e += 256)
    *(U16x8*)(kvl + e * 8) = *(const U16x8*)(kvsrc + e * 8);
  for (int e = t; e < 1024; e += 256)
    *(U16x8*)(&ql[0][0] + e * 8) = *(const U16x8*)(Q16 + (rowbase + n0) * 256 + e * 8);
  for (int e = t; e < 8192; e += 256) {
    int c = e >> 5, nn = e & 31;
    int n = n0 + nn;
    u16 v = 0;
    if (n >= 1 && n < N) {
      int p = n - 1;
      v = cvb[(size_t)(b * 256 + c) * hw64 + (p / H) * 64 + (p % H)];
    }
    cl[nn][c] = v;
  }
  __syncthreads();
  int h = t >> 5, j = t & 31;
  float kvr[32];
  #pragma unroll
  for (int k = 0; k < 32; ++k) kvr[k] = bf2f(kvl[(h * 32 + k) * 32 + j]);
  for (int nn = 0; nn < 32; ++nn) {
    int n = n0 + nn;
    if (n >= N) break;
    float fa = 0.f;
    const U16x8* qp = (const U16x8*)(&ql[nn][h * 32]);
    #pragma unroll
    for (int seg = 0; seg < 4; ++seg) {
      U16x8 qq = qp[seg];
      #pragma unroll
      for (int e = 0; e < 8; ++e) fa += bf2f(qq.d[e]) * kvr[seg * 8 + e];
    }
    float v = 0.17677669529663687f * fa + bf2f(ql[nn][t]) * bf2f(cl[nn][t]);
    attp[(rowbase + n) * 256 + t] = f2bf(v);
  }
}

// ---------------- fused cross-scale combine + LN2 (CC in bf16) ----------------
DEV float4 ld4h(const u16* p) {
  u16x4s r = *(const u16x4s*)p;
  return make_float4(bf2f(r.x), bf2f(r.y), bf2f(r.z), bf2f(r.w));
}

DEV float4 bs4h(const u16* __restrict__ base, int Hs, int oh, int ow, int Hi, int c4) {
  float scale = (float)Hs / (float)Hi;
  float sy = (oh + 0.5f) * scale - 0.5f;
  float sx = (ow + 0.5f) * scale - 0.5f;
  float fy0 = floorf(sy), fx0 = floorf(sx);
  float fy = sy - fy0, fx = sx - fx0;
  int y0 = (int)fy0, x0 = (int)fx0;
  int y0c = min(max(y0, 0), Hs - 1), y1c = min(max(y0 + 1, 0), Hs - 1);
  int x0c = min(max(x0, 0), Hs - 1), x1c = min(max(x0 + 1, 0), Hs - 1);
  const u16* ib = base + 256 + c4;
  float4 v00 = ld4h(ib + (size_t)(y0c * Hs + x0c) * 256);
  float4 v01 = ld4h(ib + (size_t)(y0c * Hs + x1c) * 256);
  float4 v10 = ld4h(ib + (size_t)(y1c * Hs + x0c) * 256);
  float4 v11 = ld4h(ib + (size_t)(y1c * Hs + x1c) * 256);
  float w00 = (1.f - fy) * (1.f - fx), w01 = (1.f - fy) * fx;
  float w10 = fy * (1.f - fx), w11 = fy * fx;
  float4 r;
  r.x = w00 * v00.x + w01 * v01.x + w10 * v10.x + w11 * v11.x;
  r.y = w00 * v00.y + w01 * v01.y + w10 * v10.y + w11 * v11.y;
  r.z = w00 * v00.z + w01 * v01.z + w10 * v10.z + w11 * v11.z;
  r.w = w00 * v00.w + w01 * v01.w + w10 * v10.w + w11 * v11.w;
  return r;
}

__global__ void combine_ln_all(float* __restrict__ XI, const u16* __restrict__ CC16,
                               const float* __restrict__ n2g, const float* __restrict__ n2b,
                               u16* __restrict__ T1) {
  int wid = threadIdx.x >> 6, lane = threadIdx.x & 63;
  int row = blockIdx.x * 4 + wid;
  if (row >= MP) return;
  int s = rs_s(row);
  int b, n; sbn(row, s, b, n);
  int N = selN(s), Hi = selH(s);
  int c4 = lane * 4;
  float4 v;
  if (n < N) {
    float4 add = ld4h(CC16 + (size_t)row * 256 + c4);
    int sa = s == 0 ? 1 : s == 1 ? 2 : s == 2 ? 3 : 2;
    int sb_ = s == 0 ? 2 : 0;
    const u16* baseA = CC16 + ((size_t)selPB(sa) + (size_t)b * selNPAD(sa)) * 256;
    const u16* baseB = CC16 + ((size_t)selPB(sb_) + (size_t)b * selNPAD(sb_)) * 256;
    if (n == 0) {
      float4 a = ld4h(baseA + c4);
      float4 bb2 = ld4h(baseB + c4);
      add.x += a.x + bb2.x; add.y += a.y + bb2.y;
      add.z += a.z + bb2.z; add.w += a.w + bb2.w;
    } else {
      int p = n - 1, oh = p / Hi, ow = p % Hi;
      float4 a = bs4h(baseA, selH(sa), oh, ow, Hi, c4);
      float4 bb2 = bs4h(baseB, selH(sb_), oh, ow, Hi, c4);
      add.x += a.x + bb2.x; add.y += a.y + bb2.y;
      add.z += a.z + bb2.z; add.w += a.w + bb2.w;
    }
    float* xp = XI + (size_t)row * 256 + c4;
    v = *(const float4*)xp;
    v.x += add.x; v.y += add.y; v.z += add.z; v.w += add.w;
    *(float4*)xp = v;
  } else {
    v = make_float4(0.f, 0.f, 0.f, 0.f);
  }
  float sm = v.x + v.y + v.z + v.w;
  #pragma unroll
  for (int off = 32; off; off >>= 1) sm += __shfl_down(sm, off);
  sm = __shfl(sm, 0);
  float mu = sm * (1.0f / 256.0f);
  float dx = v.x - mu, dy = v.y - mu, dz = v.z - mu, dw = v.w - mu;
  float q = dx * dx + dy * dy + dz * dz + dw * dw;
  #pragma unroll
  for (int off = 32; off; off >>= 1) q += __shfl_down(q, off);
  q = __shfl(q, 0);
  float rs = rsqrtf(q * (1.0f / 256.0f) + 1e-5f);
  float4 gg = *(const float4*)(n2g + s * 256 + c4);
  float4 bb = *(const float4*)(n2b + s * 256 + c4);
  u16x4s o;
  o.x = f2bf(dx * rs * gg.x + bb.x);
  o.y = f2bf(dy * rs * gg.y + bb.y);
  o.z = f2bf(dz * rs * gg.z + bb.z);
  o.w = f2bf(dw * rs * gg.w + bb.w);
  *(u16x4s*)(T1 + (size_t)row * 256 + c4) = o;
}

// ---------------- host ----------------
extern "C" void kernel_launch(void* const* d_in, const int* in_sizes, int n_in,
                              void* d_out, int out_size, void* d_ws, size_t ws_size,
                              hipStream_t stream) {
  const float* x1 = (const float*)d_in[0];
  const float* x2 = (const float*)d_in[1];
  const float* x3 = (const float*)d_in[2];
  const float* x4 = (const float*)d_in[3];
  const float* x5 = (const float*)d_in[4];
  const float* cpe_w  = (const float*)d_in[5];
  const float* cpe_b  = (const float*)d_in[6];
  const float* n1_g   = (const float*)d_in[7];
  const float* n1_b   = (const float*)d_in[8];
  const float* qkv_w  = (const float*)d_in[9];
  const float* proj_w = (const float*)d_in[10];
  const float* proj_b = (const float*)d_in[11];
  const float* crpe_w3 = (const float*)d_in[12];
  const float* crpe_b3 = (const float*)d_in[13];
  const float* crpe_w5 = (const float*)d_in[14];
  const float* crpe_b5 = (const float*)d_in[15];
  const float* crpe_w7 = (const float*)d_in[16];
  const float* crpe_b7 = (const float*)d_in[17];
  const float* n2_g   = (const float*)d_in[18];
  const float* n2_b   = (const float*)d_in[19];
  const float* fc1_w  = (const float*)d_in[20];
  const float* fc1_b  = (const float*)d_in[21];
  const float* fc2_w  = (const float*)d_in[22];
  const float* fc2_b  = (const float*)d_in[23];

  float* ws = (float*)d_ws;
  float* XI   = ws;
  u16*   CC16 = (u16*)(XI + 9437184);            // MP*256 u16 (bf16 attention-branch out)
  u16*   T1   = CC16 + 9437184;                  // MP*256 u16 (uses full f32-sized slot region)
  float* REG  = (float*)(T1 + 9437184);
  u16*   Q16  = (u16*)REG;
  u16*   KP   = Q16 + 9437184;
  u16*   VP   = KP + 9437184;
  u16*   VPI  = VP + 9437184;
  u16*   CVPI = VPI + 13762560;
  float* PRT  = (float*)CVPI;
  u16*   T2   = (u16*)REG;
  float* MX   = (float*)(CVPI + 13762560);
  float* SE   = MX + 8192;
  u16*   KVH  = (u16*)(SE + 8192);
  u16*   WQ   = KVH + 262144;
  u16*   WP   = WQ + 786432;
  u16*   W1   = WP + 262144;
  u16*   W2   = W1 + 262144;
  float* WT   = (float*)(W2 + 262144);

  float* out = (float*)d_out;

  cvt_all<<<6144, 256, 0, stream>>>(qkv_w, proj_w, fc1_w, fc2_w, WQ, WP, W1, W2);
  tpw_cpe<<<dim3(9, 4), 256, 0, stream>>>(cpe_w, WT);

  copy_f4<<<8192, 256, 0, stream>>>((const float4*)x1, (float4*)out, 25692160 / 4);

  // phase 1a: fused CPE + LN1
  cpe_ln_all<<<MP / 4, 256, 0, stream>>>(x2, x3, x4, x5, WT, cpe_b, n1_g, n1_b, XI, T1);

  // phase 1b: qkv GEMM (q row-major, k/v planar)
  qkv_gemm<<<288 * 6, 256, 0, stream>>>(T1, WQ, Q16, KP, VP);
  vimg_fill<<<8192, 256, 0, stream>>>(VP, VPI);

  // phase 1c: attention mid-section
  ksm_all<<<dim3(64, 8, 4), 256, 0, stream>>>(KP, MX, SE);
  kv_partial_all<<<2752, 1024, 0, stream>>>(KP, VP, MX, PRT);
  kv_reduce_all<<<dim3(64, 4), 1024, 0, stream>>>(PRT, SE, KVH);
  crpe_all<3, 0><<<dim3(64, 8, 5), 256, 0, stream>>>(VPI, crpe_w3, crpe_b3, CVPI, 64);
  crpe_all<5, 64><<<dim3(96, 8, 5), 256, 0, stream>>>(VPI, crpe_w5, crpe_b5, CVPI, 96);
  crpe_all<7, 160><<<dim3(96, 8, 5), 256, 0, stream>>>(VPI, crpe_w7, crpe_b7, CVPI, 96);
  att_all<<<dim3(99, 8, 4), 256, 0, stream>>>(Q16, CVPI, KVH, T1);

  // phase 1d: proj GEMM (bf16 -> CC16)
  proj_gemm<<<288 * 2, 256, 0, stream>>>(T1, WP, proj_b, CC16);

  // phase 2: fused combine + LN2 (bf16 CC)
  combine_ln_all<<<MP / 4, 256, 0, stream>>>(XI, CC16, n2_g, n2_b, T1);

  // phase 3: MLP
  gemm_std<true, true><<<288 * 8, 256, 0, stream>>>(T1, W1, fc1_b, (void*)T2, 256, 1024, 8);
  fc2_gemm<<<288 * 2, 256, 0, stream>>>(T2, W2, fc2_b, XI, out);
}

// Round 17
// 420.107 us; speedup vs baseline: 1.0663x; 1.0163x over previous
//
#include <hip/hip_runtime.h>
#include <math.h>

typedef unsigned short u16;
typedef __attribute__((ext_vector_type(8))) short bf16x8;
typedef __attribute__((ext_vector_type(4))) float f32x4;

#define MP 36864
#define OUTOFF0 25692160ull

#define DEV __device__ __forceinline__
#define AS1 __attribute__((address_space(1)))
#define AS3 __attribute__((address_space(3)))

DEV u16 f2bf(float x) {
  union { float f; unsigned u; } v; v.f = x;
  unsigned r = v.u + 0x7fffu + ((v.u >> 16) & 1u);
  return (u16)(r >> 16);
}
DEV float bf2f(u16 x) {
  union { unsigned u; float f; } v; v.u = ((unsigned)x) << 16;
  return v.f;
}

struct alignas(8) u16x4s { u16 x, y, z, w; };
struct alignas(16) U16x8 { u16 d[8]; };

DEV int rs_s(int row)   { return (row >= 25600) + (row >= 33792) + (row >= 35840); }
DEV int selPB(int s)    { return s == 0 ? 0 : s == 1 ? 25600 : s == 2 ? 33792 : 35840; }
DEV int selNPAD(int s)  { return s == 0 ? 3200 : s == 1 ? 1024 : s == 2 ? 256 : 128; }
DEV int selN(int s)     { return s == 0 ? 3137 : s == 1 ? 785 : s == 2 ? 197 : 50; }
DEV int selH(int s)     { return s == 0 ? 56 : s == 1 ? 28 : s == 2 ? 14 : 7; }
DEV int selRO(int s)    { return s == 0 ? 0 : s == 1 ? 25096 : s == 2 ? 31376 : 32952; }
DEV size_t selKPB(int s){ return s == 0 ? 0ull : s == 1 ? 6553600ull : s == 2 ? 8650752ull : 9175040ull; }
DEV size_t selVPB(int s){ return s == 0 ? 0ull : s == 1 ? 7340032ull : s == 2 ? 11010048ull : 12845056ull; }
DEV int selNC(int s)    { return s == 0 ? 32 : s == 1 ? 8 : s == 2 ? 2 : 1; }
DEV int selNCB(int s)   { return s == 0 ? 0 : s == 1 ? 2048 : s == 2 ? 2560 : 2688; }

DEV void sbn(int row, int s, int& b, int& n) {
  int l = row - selPB(s);
  if (s == 0)      { b = l / 3200; n = l - b * 3200; }
  else if (s == 1) { b = l >> 10; n = l & 1023; }
  else if (s == 2) { b = l >> 8;  n = l & 255; }
  else             { b = l >> 7;  n = l & 127; }
}

DEV int xcd_swizzle(int orig, int nblk) {
  int q = nblk >> 3, r = nblk & 7;
  int xcd = orig & 7, lin = orig >> 3;
  return (xcd < r ? xcd * (q + 1) : r * (q + 1) + (xcd - r) * q) + lin;
}

// ---------------- merged prep: x1 copy + weight cvt + cpe weight transpose ----------------
__global__ void prep_all(const float4* __restrict__ x1, float4* __restrict__ outx1, int n4,
                         const float* __restrict__ qkv_w, const float* __restrict__ proj_w,
                         const float* __restrict__ fc1_w, const float* __restrict__ fc2_w,
                         u16* __restrict__ WQ, u16* __restrict__ WP,
                         u16* __restrict__ W1, u16* __restrict__ W2,
                         const float* __restrict__ cpe_w, float* __restrict__ WT) {
  int bid = blockIdx.x, t = threadIdx.x;
  if (bid < 8192) {
    for (int i = bid * 256 + t; i < n4; i += 8192 * 256) outx1[i] = x1[i];
  } else if (bid < 14336) {
    int i = (bid - 8192) * 256 + t;
    if (i < 786432) WQ[i] = f2bf(qkv_w[i]);
    else if (i < 1048576) WP[i - 786432] = f2bf(proj_w[i - 786432]);
    else if (i < 1310720) W1[i - 1048576] = f2bf(fc1_w[i - 1048576]);
    else W2[i - 1310720] = f2bf(fc2_w[i - 1310720]);
  } else {
    int b9 = bid - 14336;
    int i = b9 / 9;
    int e = (b9 % 9) * 256 + t;
    if (e < 2304) {
      int c = e / 9, k = e % 9;
      WT[i * 2304 + k * 256 + c] = cpe_w[i * 2304 + c * 9 + k];
    }
  }
}

// ---------------- fused CPE + LN1 (wave per padded row) ----------------
__global__ void cpe_ln_all(const float* __restrict__ x2, const float* __restrict__ x3,
                           const float* __restrict__ x4, const float* __restrict__ x5,
                           const float* __restrict__ WT, const float* __restrict__ cpe_b,
                           const float* __restrict__ n1g, const float* __restrict__ n1b,
                           float* __restrict__ XI, u16* __restrict__ T1) {
  int wid = threadIdx.x >> 6, lane = threadIdx.x & 63;
  int row = blockIdx.x * 4 + wid;
  if (row >= MP) return;
  int s = rs_s(row);
  int b, n; sbn(row, s, b, n);
  int N = selN(s), H = selH(s);
  int c4 = lane * 4;
  float4 v = make_float4(0.f, 0.f, 0.f, 0.f);
  if (n < N) {
    const float* x = s == 0 ? x2 : s == 1 ? x3 : s == 2 ? x4 : x5;
    v = *(const float4*)(x + ((size_t)b * N + n) * 256 + c4);
    if (n > 0) {
      int p = n - 1, h0 = p / H, w0 = p % H;
      float4 acc = *(const float4*)(cpe_b + s * 256 + c4);
      const float* wT = WT + s * 2304;
      #pragma unroll
      for (int kh = 0; kh < 3; ++kh) {
        int hh = h0 + kh - 1;
        if (hh < 0 || hh >= H) continue;
        #pragma unroll
        for (int kw = 0; kw < 3; ++kw) {
          int ww = w0 + kw - 1;
          if (ww < 0 || ww >= H) continue;
          float4 t = *(const float4*)(x + ((size_t)b * N + 1 + hh * H + ww) * 256 + c4);
          float4 wv = *(const float4*)(wT + (kh * 3 + kw) * 256 + c4);
          acc.x += t.x * wv.x; acc.y += t.y * wv.y;
          acc.z += t.z * wv.z; acc.w += t.w * wv.w;
        }
      }
      v.x += acc.x; v.y += acc.y; v.z += acc.z; v.w += acc.w;
    }
  }
  *(float4*)(XI + (size_t)row * 256 + c4) = v;
  float sm = v.x + v.y + v.z + v.w;
  #pragma unroll
  for (int off = 32; off; off >>= 1) sm += __shfl_down(sm, off);
  sm = __shfl(sm, 0);
  float mu = sm * (1.0f / 256.0f);
  float dx = v.x - mu, dy = v.y - mu, dz = v.z - mu, dw = v.w - mu;
  float q = dx * dx + dy * dy + dz * dz + dw * dw;
  #pragma unroll
  for (int off = 32; off; off >>= 1) q += __shfl_down(q, off);
  q = __shfl(q, 0);
  float rs = rsqrtf(q * (1.0f / 256.0f) + 1e-5f);
  float4 gg = *(const float4*)(n1g + s * 256 + c4);
  float4 bb = *(const float4*)(n1b + s * 256 + c4);
  u16x4s o;
  o.x = f2bf(dx * rs * gg.x + bb.x);
  o.y = f2bf(dy * rs * gg.y + bb.y);
  o.z = f2bf(dz * rs * gg.z + bb.z);
  o.w = f2bf(dw * rs * gg.w + bb.w);
  *(u16x4s*)(T1 + (size_t)row * 256 + c4) = o;
}

// ---------------- GEMM: BK=32, 3-buffer depth-2 pipeline, counted vmcnt ----------------
DEV void stage32(const u16* __restrict__ A, const u16* __restrict__ W,
                 u16* dst, int bm, int bn, int K, int k0) {
  int t = threadIdx.x, wv = t >> 6;
  u16* aD = dst;
  u16* bD = dst + 4096;
  #pragma unroll
  for (int iss = 0; iss < 2; ++iss) {
    int sI = iss * 256 + t;
    int row = sI >> 2, g = sI & 3;
    int gel = ((g ^ (row & 3)) << 3);
    __builtin_amdgcn_global_load_lds(
        (const AS1 void*)(A + (size_t)(bm + row) * K + k0 + gel),
        (AS3 void*)(aD + (size_t)(iss * 256 + wv * 64) * 8), 16, 0, 0);
    __builtin_amdgcn_global_load_lds(
        (const AS1 void*)(W + (size_t)(bn + row) * K + k0 + gel),
        (AS3 void*)(bD + (size_t)(iss * 256 + wv * 64) * 8), 16, 0, 0);
  }
}

DEV void mainloop(const u16* __restrict__ A, const u16* __restrict__ W, int K,
                  int bm, int bn, u16* lds, f32x4 (&acc)[4][4]) {
  int t = threadIdx.x, lane = t & 63, wv = t >> 6;
  int wr = wv >> 1, wc = wv & 1;
  const int nt = K >> 5;
  stage32(A, W, lds, bm, bn, K, 0);
  stage32(A, W, lds + 8192, bm, bn, K, 32);
  int buf = 0;
  for (int tt = 0; tt < nt; ++tt) {
    if (tt + 1 < nt) asm volatile("s_waitcnt vmcnt(4)" ::: "memory");
    else             asm volatile("s_waitcnt vmcnt(0)" ::: "memory");
    __builtin_amdgcn_s_barrier();
    asm volatile("" ::: "memory");
    if (tt + 2 < nt) {
      int nb = buf + 2; if (nb >= 3) nb -= 3;
      stage32(A, W, lds + nb * 8192, bm, bn, K, (tt + 2) << 5);
    }
    const u16* aS = lds + buf * 8192;
    const u16* bS = aS + 4096;
    bf16x8 af[4], bfr[4];
    #pragma unroll
    for (int m = 0; m < 4; ++m) {
      int row = wr * 64 + m * 16 + (lane & 15);
      int sg = (lane >> 4) ^ (row & 3);
      af[m] = *(const bf16x8*)(aS + row * 32 + sg * 8);
    }
    #pragma unroll
    for (int n = 0; n < 4; ++n) {
      int row = wc * 64 + n * 16 + (lane & 15);
      int sg = (lane >> 4) ^ (row & 3);
      bfr[n] = *(const bf16x8*)(bS + row * 32 + sg * 8);
    }
    #pragma unroll
    for (int m = 0; m < 4; ++m)
      #pragma unroll
      for (int n = 0; n < 4; ++n)
        acc[m][n] = __builtin_amdgcn_mfma_f32_16x16x32_bf16(af[m], bfr[n], acc[m][n], 0, 0, 0);
    buf += 1; if (buf >= 3) buf -= 3;
  }
}

DEV void epi_dump(const f32x4 (&acc)[4][4], int pass, float* eps) {
  int t = threadIdx.x, lane = t & 63, wv = t >> 6;
  int wr = wv >> 1, wc = wv & 1;
  if (wr != (pass >> 1)) return;
  #pragma unroll
  for (int mh = 0; mh < 2; ++mh) {
    int m = (pass & 1) * 2 + mh;
    #pragma unroll
    for (int n = 0; n < 4; ++n) {
      int col = wc * 64 + n * 16 + (lane & 15);
      #pragma unroll
      for (int rg = 0; rg < 4; ++rg)
        eps[(mh * 16 + ((lane >> 4) << 2) + rg) * 132 + col] = acc[m][n][rg];
    }
  }
}

template <bool GELU, bool BF16>
DEV void epi_rowmajor(const float* eps, int pass, void* outp, const float* bias,
                      int bm, int bn, int Nout) {
  int t = threadIdx.x;
  int lr = t >> 3, cb = (t & 7) * 4;
  int gr = bm + pass * 32 + lr;
  #pragma unroll
  for (int j = 0; j < 4; ++j) {
    int col = cb + j * 32;
    float4 f = *(const float4*)(eps + lr * 132 + col);
    int gc = bn + col;
    if (bias) {
      float4 bv = *(const float4*)(bias + gc);
      f.x += bv.x; f.y += bv.y; f.z += bv.z; f.w += bv.w;
    }
    if (GELU) {
      f.x /= (1.0f + __expf(-1.702f * f.x));
      f.y /= (1.0f + __expf(-1.702f * f.y));
      f.z /= (1.0f + __expf(-1.702f * f.z));
      f.w /= (1.0f + __expf(-1.702f * f.w));
    }
    if (BF16) {
      u16x4s p;
      p.x = f2bf(f.x); p.y = f2bf(f.y); p.z = f2bf(f.z); p.w = f2bf(f.w);
      *(u16x4s*)((u16*)outp + (size_t)gr * Nout + gc) = p;
    } else {
      *(float4*)((float*)outp + (size_t)gr * Nout + gc) = f;
    }
  }
}

// ---------------- standard GEMM (fc1) ----------------
template <bool GELU, bool BF16>
__launch_bounds__(256, 3)
__global__ void gemm_std(const u16* __restrict__ A, const u16* __restrict__ W,
                         const float* __restrict__ bias, void* __restrict__ outp,
                         int K, int Nout, int nnt) {
  __shared__ __align__(16) u16 lds[24576];
  int wg = xcd_swizzle(blockIdx.x, gridDim.x);
  int bm = (wg / nnt) << 7, bn = (wg % nnt) << 7;
  f32x4 acc[4][4] = {};
  mainloop(A, W, K, bm, bn, lds, acc);
  float* eps = (float*)lds;
  #pragma unroll
  for (int pass = 0; pass < 4; ++pass) {
    __syncthreads();
    epi_dump(acc, pass, eps);
    __syncthreads();
    epi_rowmajor<GELU, BF16>(eps, pass, outp, bias, bm, bn, Nout);
  }
}

// ---------------- qkv GEMM: q row-major bf16; k,v planar-transposed ----------------
__launch_bounds__(256, 3)
__global__ void qkv_gemm(const u16* __restrict__ A, const u16* __restrict__ WQ,
                         u16* __restrict__ Q16, u16* __restrict__ KP,
                         u16* __restrict__ VP) {
  __shared__ __align__(16) u16 lds[24576];
  int wg = xcd_swizzle(blockIdx.x, gridDim.x);
  int mt = wg / 6, ct = wg % 6;
  int bm = mt << 7, bn = ct << 7;
  int s = rs_s(bm);
  f32x4 acc[4][4] = {};
  mainloop(A, WQ + (size_t)s * 196608, 256, bm, bn, lds, acc);
  float* eps = (float*)lds;
  int b, nb; sbn(bm, s, b, nb);
  int NPAD = selNPAD(s);
  #pragma unroll
  for (int pass = 0; pass < 4; ++pass) {
    __syncthreads();
    epi_dump(acc, pass, eps);
    __syncthreads();
    if (ct < 2) {
      epi_rowmajor<false, true>(eps, pass, Q16, nullptr, bm, bn, 256);
    } else {
      int t = threadIdx.x;
      int c = t >> 1, half = t & 1;
      bool isK = (ct < 4);
      int cg = bn - (isK ? 256 : 512) + c;
      int n0 = nb + pass * 32 + half * 16;
      float vals[16];
      #pragma unroll
      for (int r = 0; r < 16; ++r) vals[r] = eps[(half * 16 + r) * 132 + c];
      U16x8 p0, p1;
      #pragma unroll
      for (int e = 0; e < 8; ++e) { p0.d[e] = f2bf(vals[e]); p1.d[e] = f2bf(vals[8 + e]); }
      u16* pbase = (isK ? KP : VP) + selKPB(s) + (size_t)(b * 256 + cg) * NPAD + n0;
      *(U16x8*)pbase = p0;
      *(U16x8*)(pbase + 8) = p1;
    }
  }
}

// ---------------- proj GEMM (bf16 out into CC16) ----------------
__launch_bounds__(256, 3)
__global__ void proj_gemm(const u16* __restrict__ A, const u16* __restrict__ WP,
                          const float* __restrict__ proj_b, u16* __restrict__ CC16) {
  __shared__ __align__(16) u16 lds[24576];
  int wg = xcd_swizzle(blockIdx.x, gridDim.x);
  int bm = (wg >> 1) << 7, bn = (wg & 1) << 7;
  int s = rs_s(bm);
  f32x4 acc[4][4] = {};
  mainloop(A, WP + (size_t)s * 65536, 256, bm, bn, lds, acc);
  float* eps = (float*)lds;
  #pragma unroll
  for (int pass = 0; pass < 4; ++pass) {
    __syncthreads();
    epi_dump(acc, pass, eps);
    __syncthreads();
    epi_rowmajor<false, true>(eps, pass, CC16, proj_b + s * 256, bm, bn, 256);
  }
}

// ---------------- fc2 GEMM: +bias +XI residual, remapped f32 out ----------------
__launch_bounds__(256, 3)
__global__ void fc2_gemm(const u16* __restrict__ A, const u16* __restrict__ W2,
                         const float* __restrict__ fc2_b, const float* __restrict__ XI,
                         float* __restrict__ out) {
  __shared__ __align__(16) u16 lds[24576];
  int wg = xcd_swizzle(blockIdx.x, gridDim.x);
  int bm = (wg >> 1) << 7, bn = (wg & 1) << 7;
  f32x4 acc[4][4] = {};
  mainloop(A, W2, 1024, bm, bn, lds, acc);
  float* eps = (float*)lds;
  int s = rs_s(bm);
  int b, nb; sbn(bm, s, b, nb);
  int N = selN(s), RO = selRO(s);
  #pragma unroll
  for (int pass = 0; pass < 4; ++pass) {
    __syncthreads();
    epi_dump(acc, pass, eps);
    __syncthreads();
    int t = threadIdx.x;
    int lr = t >> 3, cb = (t & 7) * 4;
    int n = nb + pass * 32 + lr;
    if (n >= N) continue;
    int prow = bm + pass * 32 + lr;
    size_t orow = (size_t)RO + (size_t)b * N + n;
    #pragma unroll
    for (int j = 0; j < 4; ++j) {
      int col = cb + j * 32;
      float4 f = *(const float4*)(eps + lr * 132 + col);
      int gc = bn + col;
      float4 bv = *(const float4*)(fc2_b + gc);
      float4 rv = *(const float4*)(XI + (size_t)prow * 256 + gc);
      f.x += bv.x + rv.x; f.y += bv.y + rv.y;
      f.z += bv.z + rv.z; f.w += bv.w + rv.w;
      *(float4*)(out + OUTOFF0 + orow * 256 + gc) = f;
    }
  }
}

// ---------------- merged: padded V-image fill + k softmax stats ----------------
DEV void vimg_one(const u16* __restrict__ VP, u16* __restrict__ VPI, int plane) {
  int s = plane >> 11;
  int pc = plane & 2047;
  int H = selH(s), NPAD = selNPAD(s);
  const u16* vp = VP + selKPB(s) + (size_t)pc * NPAD;
  u16* vi = VPI + selVPB(s) + (size_t)pc * (H * 64);
  int tot = H * 64;
  for (int e = threadIdx.x; e < tot; e += 256) {
    int h = e >> 6, w = e & 63;
    vi[e] = (w < H) ? vp[1 + h * H + w] : (u16)0;
  }
}

DEV void ksm_one(const u16* __restrict__ KP, float* __restrict__ mx, float* __restrict__ se,
                 int xblk, int b, int s) {
  int N = selN(s), NPAD = selNPAD(s);
  int wv = threadIdx.x >> 6, lane = threadIdx.x & 63;
  int cg = xblk * 4 + wv;
  const u16* kp = KP + selKPB(s) + (size_t)(b * 256 + cg) * NPAD;
  float m = -1e30f, sm = 0.f;
  for (int n = lane; n < N; n += 64) {
    float v = bf2f(kp[n]);
    float nm = fmaxf(m, v);
    sm = sm * __expf(m - nm) + __expf(v - nm);
    m = nm;
  }
  #pragma unroll
  for (int off = 1; off < 64; off <<= 1) {
    float mo = __shfl_xor(m, off), so = __shfl_xor(sm, off);
    float nm = fmaxf(m, mo);
    sm = sm * __expf(m - nm) + so * __expf(mo - nm);
    m = nm;
  }
  if (lane == 0) { mx[s * 2048 + b * 256 + cg] = m; se[s * 2048 + b * 256 + cg] = sm; }
}

__global__ void vksm_pack(const u16* __restrict__ VP, u16* __restrict__ VPI,
                          const u16* __restrict__ KP, float* __restrict__ mx,
                          float* __restrict__ se) {
  int bid = blockIdx.x;
  if (bid < 8192) {
    vimg_one(VP, VPI, bid);
  } else {
    int r = bid - 8192;           // 2048 = 64 x 8 x 4
    ksm_one(KP, mx, se, r & 63, (r >> 6) & 7, r >> 9);
  }
}

// ---------------- kv partials ----------------
__launch_bounds__(1024)
__global__ void kv_partial_all(const u16* __restrict__ KP, const u16* __restrict__ VP,
                               const float* __restrict__ mx, float* __restrict__ part) {
  __shared__ float kl[32][65];
  __shared__ float vl[32][65];
  int blk = blockIdx.x;
  int s = (blk >= selNCB(1)) + (blk >= selNCB(2)) + (blk >= selNCB(3));
  int local = blk - selNCB(s);
  int NC = selNC(s);
  int chunk = local % NC;
  int bh = local / NC;
  int b = bh >> 3, h = bh & 7;
  int N = selN(s), NPAD = selNPAD(s);
  int chunkrows = (N + NC - 1) / NC;
  const u16* kpb = KP + selKPB(s);
  const u16* vpb = VP + selKPB(s);
  int t = threadIdx.x;
  int i = t >> 5, j = t & 31;
  float acc = 0.f;
  int n0s = chunk * chunkrows, n1s = min(N, n0s + chunkrows);
  for (int n0 = n0s; n0 < n1s; n0 += 64) {
    #pragma unroll
    for (int e = t; e < 2048; e += 1024) {
      int c = e >> 6, nn = e & 63;
      int n = n0 + nn;
      bool ok = (n < n1s);
      kl[c][nn] = ok ? bf2f(kpb[(size_t)(b * 256 + h * 32 + c) * NPAD + n]) : -1e30f;
      vl[c][nn] = ok ? bf2f(vpb[(size_t)(b * 256 + h * 32 + c) * NPAD + n]) : 0.f;
    }
    __syncthreads();
    #pragma unroll
    for (int e = t; e < 2048; e += 1024) {
      int c = e >> 6, nn = e & 63;
      kl[c][nn] = __expf(kl[c][nn] - mx[s * 2048 + b * 256 + h * 32 + c]);
    }
    __syncthreads();
    #pragma unroll
    for (int nn = 0; nn < 64; ++nn) acc += kl[i][nn] * vl[j][nn];
    __syncthreads();
  }
  part[(size_t)blk * 1024 + t] = acc;
}

// ---------------- merged: CRPE (3/5/7) + kv reduce ----------------
template <int KS, int C0>
DEV void crpe_one(const u16* __restrict__ VPI, const float* __restrict__ w,
                  const float* __restrict__ bias, u16* __restrict__ CVPI, int CS,
                  int c, int b, int sub) {
  constexpr int pad = KS / 2;
  int s = (sub >= 2) + (sub >= 3) + (sub >= 4);
  int z = sub - (s == 0 ? 0 : s + 1);
  int RS = (s == 0) ? 2 : 1;
  int H = selH(s);
  int G = (H + 7) >> 3;
  int hpb = (H + RS - 1) / RS;
  int h0b = z * hpb;
  int h1b = min(H, h0b + hpb);
  size_t plane = selVPB(s) + (size_t)(b * 256 + C0 + c) * (size_t)(H * 64);
  const u16* vp = VPI + plane;
  u16* op = CVPI + plane;
  float wreg[KS * KS];
  #pragma unroll
  for (int e = 0; e < KS * KS; ++e) wreg[e] = w[(s * CS + c) * KS * KS + e];
  float bb = bias[s * CS + c];
  int ntask = (h1b - h0b) * G;
  for (int task = threadIdx.x; task < ntask; task += 256) {
    int g = task % G;
    int h = h0b + task / G;
    int w0 = g << 3;
    float o[8];
    #pragma unroll
    for (int e = 0; e < 8; ++e) o[e] = bb;
    #pragma unroll
    for (int kh = 0; kh < KS; ++kh) {
      int hh = h + kh - pad;
      if (hh < 0 || hh >= H) continue;
      const u16* rowp = vp + hh * 64;
      U16x8 ch0 = {}, ch1, ch2;
      if (w0 >= 8) ch0 = *(const U16x8*)(rowp + w0 - 8);
      ch1 = *(const U16x8*)(rowp + w0);
      ch2 = *(const U16x8*)(rowp + w0 + 8);
      float tv[24];
      #pragma unroll
      for (int j2 = 8 - pad; j2 <= 15 + pad; ++j2) {
        u16 raw = (j2 < 8) ? ch0.d[j2] : (j2 < 16 ? ch1.d[j2 - 8] : ch2.d[j2 - 16]);
        tv[j2] = bf2f(raw);
      }
      #pragma unroll
      for (int kw = 0; kw < KS; ++kw) {
        float wv = wreg[kh * KS + kw];
        #pragma unroll
        for (int e = 0; e < 8; ++e) o[e] += tv[8 + e + kw - pad] * wv;
      }
    }
    U16x8 pk;
    #pragma unroll
    for (int e = 0; e < 8; ++e) pk.d[e] = f2bf(o[e]);
    *(U16x8*)(op + h * 64 + w0) = pk;
  }
}

DEV void kv_reduce_one(const float* __restrict__ part, const float* __restrict__ se,
                       u16* __restrict__ kvh, int bh, int s) {
  int NC = selNC(s), base = selNCB(s);
  int b = bh >> 3, h = bh & 7;
  for (int tt = threadIdx.x; tt < 1024; tt += 256) {
    int i = tt >> 5;
    float sm = 0.f;
    for (int c = 0; c < NC; ++c) sm += part[(size_t)(base + bh * NC + c) * 1024 + tt];
    kvh[(size_t)s * 65536 + bh * 1024 + tt] = f2bf(sm / se[s * 2048 + b * 256 + h * 32 + i]);
  }
}

__global__ void crpe_pack(const u16* __restrict__ VPI,
                          const float* __restrict__ w3, const float* __restrict__ b3,
                          const float* __restrict__ w5, const float* __restrict__ b5,
                          const float* __restrict__ w7, const float* __restrict__ b7,
                          u16* __restrict__ CVPI,
                          const float* __restrict__ PRT, const float* __restrict__ SE,
                          u16* __restrict__ KVH) {
  int bid = blockIdx.x;
  if (bid < 2560) {                         // 64 x 8 x 5
    crpe_one<3, 0>(VPI, w3, b3, CVPI, 64, bid & 63, (bid >> 6) & 7, bid >> 9);
  } else if (bid < 6400) {                  // 96 x 8 x 5
    int r = bid - 2560;
    crpe_one<5, 64>(VPI, w5, b5, CVPI, 96, r % 96, (r / 96) & 7, r / 768);
  } else if (bid < 10240) {
    int r = bid - 6400;
    crpe_one<7, 160>(VPI, w7, b7, CVPI, 96, r % 96, (r / 96) & 7, r / 768);
  } else {                                   // 256 = 64 bh x 4 s
    int r = bid - 10240;
    kv_reduce_one(PRT, SE, KVH, r & 63, r >> 6);
  }
}

// ---------------- att: 32 tokens/block, bf16 LDS, kv column in registers ----------------
__launch_bounds__(256, 3)
__global__ void att_all(const u16* __restrict__ Q16, const u16* __restrict__ CVPI,
                        const u16* __restrict__ kvh, u16* __restrict__ attp) {
  int s = blockIdx.z, b = blockIdx.y;
  int N = selN(s), H = selH(s);
  int n0 = blockIdx.x * 32;
  if (n0 >= N) return;
  __shared__ u16 kvl[8192];
  __shared__ u16 ql[32][256];
  __shared__ u16 cl[32][256];
  int t = threadIdx.x;
  int hw64 = H * 64;
  size_t rowbase = (size_t)selPB(s) + (size_t)b * selNPAD(s);
  const u16* cvb = CVPI + selVPB(s);
  const u16* kvsrc = kvh + (size_t)s * 65536 + (size_t)b * 8192;
  for (int e = t; e < 1024; e += 256)
    *(U16x8*)(kvl + e * 8) = *(const U16x8*)(kvsrc + e * 8);
  for (int e = t; e < 1024; e += 256)
    *(U16x8*)(&ql[0][0] + e * 8) = *(const U16x8*)(Q16 + (rowbase + n0) * 256 + e * 8);
  for (int e = t; e < 8192; e += 256) {
    int c = e >> 5, nn = e & 31;
    int n = n0 + nn;
    u16 v = 0;
    if (n >= 1 && n < N) {
      int p = n - 1;
      v = cvb[(size_t)(b * 256 + c) * hw64 + (p / H) * 64 + (p % H)];
    }
    cl[nn][c] = v;
  }
  __syncthreads();
  int h = t >> 5, j = t & 31;
  float kvr[32];
  #pragma unroll
  for (int k = 0; k < 32; ++k) kvr[k] = bf2f(kvl[(h * 32 + k) * 32 + j]);
  for (int nn = 0; nn < 32; ++nn) {
    int n = n0 + nn;
    if (n >= N) break;
    float fa = 0.f;
    const U16x8* qp = (const U16x8*)(&ql[nn][h * 32]);
    #pragma unroll
    for (int seg = 0; seg < 4; ++seg) {
      U16x8 qq = qp[seg];
      #pragma unroll
      for (int e = 0; e < 8; ++e) fa += bf2f(qq.d[e]) * kvr[seg * 8 + e];
    }
    float v = 0.17677669529663687f * fa + bf2f(ql[nn][t]) * bf2f(cl[nn][t]);
    attp[(rowbase + n) * 256 + t] = f2bf(v);
  }
}

// ---------------- fused cross-scale combine + LN2 (CC in bf16) ----------------
DEV float4 ld4h(const u16* p) {
  u16x4s r = *(const u16x4s*)p;
  return make_float4(bf2f(r.x), bf2f(r.y), bf2f(r.z), bf2f(r.w));
}

DEV float4 bs4h(const u16* __restrict__ base, int Hs, int oh, int ow, int Hi, int c4) {
  float scale = (float)Hs / (float)Hi;
  float sy = (oh + 0.5f) * scale - 0.5f;
  float sx = (ow + 0.5f) * scale - 0.5f;
  float fy0 = floorf(sy), fx0 = floorf(sx);
  float fy = sy - fy0, fx = sx - fx0;
  int y0 = (int)fy0, x0 = (int)fx0;
  int y0c = min(max(y0, 0), Hs - 1), y1c = min(max(y0 + 1, 0), Hs - 1);
  int x0c = min(max(x0, 0), Hs - 1), x1c = min(max(x0 + 1, 0), Hs - 1);
  const u16* ib = base + 256 + c4;
  float4 v00 = ld4h(ib + (size_t)(y0c * Hs + x0c) * 256);
  float4 v01 = ld4h(ib + (size_t)(y0c * Hs + x1c) * 256);
  float4 v10 = ld4h(ib + (size_t)(y1c * Hs + x0c) * 256);
  float4 v11 = ld4h(ib + (size_t)(y1c * Hs + x1c) * 256);
  float w00 = (1.f - fy) * (1.f - fx), w01 = (1.f - fy) * fx;
  float w10 = fy * (1.f - fx), w11 = fy * fx;
  float4 r;
  r.x = w00 * v00.x + w01 * v01.x + w10 * v10.x + w11 * v11.x;
  r.y = w00 * v00.y + w01 * v01.y + w10 * v10.y + w11 * v11.y;
  r.z = w00 * v00.z + w01 * v01.z + w10 * v10.z + w11 * v11.z;
  r.w = w00 * v00.w + w01 * v01.w + w10 * v10.w + w11 * v11.w;
  return r;
}

__global__ void combine_ln_all(float* __restrict__ XI, const u16* __restrict__ CC16,
                               const float* __restrict__ n2g, const float* __restrict__ n2b,
                               u16* __restrict__ T1) {
  int wid = threadIdx.x >> 6, lane = threadIdx.x & 63;
  int row = blockIdx.x * 4 + wid;
  if (row >= MP) return;
  int s = rs_s(row);
  int b, n; sbn(row, s, b, n);
  int N = selN(s), Hi = selH(s);
  int c4 = lane * 4;
  float4 v;
  if (n < N) {
    float4 add = ld4h(CC16 + (size_t)row * 256 + c4);
    int sa = s == 0 ? 1 : s == 1 ? 2 : s == 2 ? 3 : 2;
    int sb_ = s == 0 ? 2 : 0;
    const u16* baseA = CC16 + ((size_t)selPB(sa) + (size_t)b * selNPAD(sa)) * 256;
    const u16* baseB = CC16 + ((size_t)selPB(sb_) + (size_t)b * selNPAD(sb_)) * 256;
    if (n == 0) {
      float4 a = ld4h(baseA + c4);
      float4 bb2 = ld4h(baseB + c4);
      add.x += a.x + bb2.x; add.y += a.y + bb2.y;
      add.z += a.z + bb2.z; add.w += a.w + bb2.w;
    } else {
      int p = n - 1, oh = p / Hi, ow = p % Hi;
      float4 a = bs4h(baseA, selH(sa), oh, ow, Hi, c4);
      float4 bb2 = bs4h(baseB, selH(sb_), oh, ow, Hi, c4);
      add.x += a.x + bb2.x; add.y += a.y + bb2.y;
      add.z += a.z + bb2.z; add.w += a.w + bb2.w;
    }
    float* xp = XI + (size_t)row * 256 + c4;
    v = *(const float4*)xp;
    v.x += add.x; v.y += add.y; v.z += add.z; v.w += add.w;
    *(float4*)xp = v;
  } else {
    v = make_float4(0.f, 0.f, 0.f, 0.f);
  }
  float sm = v.x + v.y + v.z + v.w;
  #pragma unroll
  for (int off = 32; off; off >>= 1) sm += __shfl_down(sm, off);
  sm = __shfl(sm, 0);
  float mu = sm * (1.0f / 256.0f);
  float dx = v.x - mu, dy = v.y - mu, dz = v.z - mu, dw = v.w - mu;
  float q = dx * dx + dy * dy + dz * dz + dw * dw;
  #pragma unroll
  for (int off = 32; off; off >>= 1) q += __shfl_down(q, off);
  q = __shfl(q, 0);
  float rs = rsqrtf(q * (1.0f / 256.0f) + 1e-5f);
  float4 gg = *(const float4*)(n2g + s * 256 + c4);
  float4 bb = *(const float4*)(n2b + s * 256 + c4);
  u16x4s o;
  o.x = f2bf(dx * rs * gg.x + bb.x);
  o.y = f2bf(dy * rs * gg.y + bb.y);
  o.z = f2bf(dz * rs * gg.z + bb.z);
  o.w = f2bf(dw * rs * gg.w + bb.w);
  *(u16x4s*)(T1 + (size_t)row * 256 + c4) = o;
}

// ---------------- host ----------------
extern "C" void kernel_launch(void* const* d_in, const int* in_sizes, int n_in,
                              void* d_out, int out_size, void* d_ws, size_t ws_size,
                              hipStream_t stream) {
  const float* x1 = (const float*)d_in[0];
  const float* x2 = (const float*)d_in[1];
  const float* x3 = (const float*)d_in[2];
  const float* x4 = (const float*)d_in[3];
  const float* x5 = (const float*)d_in[4];
  const float* cpe_w  = (const float*)d_in[5];
  const float* cpe_b  = (const float*)d_in[6];
  const float* n1_g   = (const float*)d_in[7];
  const float* n1_b   = (const float*)d_in[8];
  const float* qkv_w  = (const float*)d_in[9];
  const float* proj_w = (const float*)d_in[10];
  const float* proj_b = (const float*)d_in[11];
  const float* crpe_w3 = (const float*)d_in[12];
  const float* crpe_b3 = (const float*)d_in[13];
  const float* crpe_w5 = (const float*)d_in[14];
  const float* crpe_b5 = (const float*)d_in[15];
  const float* crpe_w7 = (const float*)d_in[16];
  const float* crpe_b7 = (const float*)d_in[17];
  const float* n2_g   = (const float*)d_in[18];
  const float* n2_b   = (const float*)d_in[19];
  const float* fc1_w  = (const float*)d_in[20];
  const float* fc1_b  = (const float*)d_in[21];
  const float* fc2_w  = (const float*)d_in[22];
  const float* fc2_b  = (const float*)d_in[23];

  float* ws = (float*)d_ws;
  float* XI   = ws;
  u16*   CC16 = (u16*)(XI + 9437184);
  u16*   T1   = CC16 + 9437184;
  float* REG  = (float*)(T1 + 9437184);
  u16*   Q16  = (u16*)REG;
  u16*   KP   = Q16 + 9437184;
  u16*   VP   = KP + 9437184;
  u16*   VPI  = VP + 9437184;
  u16*   CVPI = VPI + 13762560;
  float* PRT  = (float*)CVPI;
  u16*   T2   = (u16*)REG;
  float* MX   = (float*)(CVPI + 13762560);
  float* SE   = MX + 8192;
  u16*   KVH  = (u16*)(SE + 8192);
  u16*   WQ   = KVH + 262144;
  u16*   WP   = WQ + 786432;
  u16*   W1   = WP + 262144;
  u16*   W2   = W1 + 262144;
  float* WT   = (float*)(W2 + 262144);

  float* out = (float*)d_out;

  // prep: x1 copy + weight cvt + cpe weight transpose (one dispatch)
  prep_all<<<14372, 256, 0, stream>>>((const float4*)x1, (float4*)out, 25692160 / 4,
                                      qkv_w, proj_w, fc1_w, fc2_w, WQ, WP, W1, W2,
                                      cpe_w, WT);

  // phase 1a: fused CPE + LN1
  cpe_ln_all<<<MP / 4, 256, 0, stream>>>(x2, x3, x4, x5, WT, cpe_b, n1_g, n1_b, XI, T1);

  // phase 1b: qkv GEMM (q row-major, k/v planar)
  qkv_gemm<<<288 * 6, 256, 0, stream>>>(T1, WQ, Q16, KP, VP);

  // phase 1c: attention mid-section (merged dispatches)
  vksm_pack<<<10240, 256, 0, stream>>>(VP, VPI, KP, MX, SE);
  kv_partial_all<<<2752, 1024, 0, stream>>>(KP, VP, MX, PRT);
  crpe_pack<<<10496, 256, 0, stream>>>(VPI, crpe_w3, crpe_b3, crpe_w5, crpe_b5,
                                       crpe_w7, crpe_b7, CVPI, PRT, SE, KVH);
  att_all<<<dim3(99, 8, 4), 256, 0, stream>>>(Q16, CVPI, KVH, T1);

  // phase 1d: proj GEMM (bf16 -> CC16)
  proj_gemm<<<288 * 2, 256, 0, stream>>>(T1, WP, proj_b, CC16);

  // phase 2: fused combine + LN2 (bf16 CC)
  combine_ln_all<<<MP / 4, 256, 0, stream>>>(XI, CC16, n2_g, n2_b, T1);

  // phase 3: MLP
  gemm_std<true, true><<<288 * 8, 256, 0, stream>>>(T1, W1, fc1_b, (void*)T2, 256, 1024, 8);
  fc2_gemm<<<288 * 2, 256, 0, stream>>>(T2, W2, fc2_b, XI, out);
}

// Round 18
// 419.695 us; speedup vs baseline: 1.0673x; 1.0010x over previous
//
#include <hip/hip_runtime.h>
#include <math.h>

typedef unsigned short u16;
typedef __attribute__((ext_vector_type(8))) short bf16x8;
typedef __attribute__((ext_vector_type(4))) float f32x4;

#define MP 36864
#define OUTOFF0 25692160ull

#define DEV __device__ __forceinline__
#define AS1 __attribute__((address_space(1)))
#define AS3 __attribute__((address_space(3)))

DEV u16 f2bf(float x) {
  union { float f; unsigned u; } v; v.f = x;
  unsigned r = v.u + 0x7fffu + ((v.u >> 16) & 1u);
  return (u16)(r >> 16);
}
DEV float bf2f(u16 x) {
  union { unsigned u; float f; } v; v.u = ((unsigned)x) << 16;
  return v.f;
}

struct alignas(8) u16x4s { u16 x, y, z, w; };
struct alignas(16) U16x8 { u16 d[8]; };

DEV int rs_s(int row)   { return (row >= 25600) + (row >= 33792) + (row >= 35840); }
DEV int selPB(int s)    { return s == 0 ? 0 : s == 1 ? 25600 : s == 2 ? 33792 : 35840; }
DEV int selNPAD(int s)  { return s == 0 ? 3200 : s == 1 ? 1024 : s == 2 ? 256 : 128; }
DEV int selN(int s)     { return s == 0 ? 3137 : s == 1 ? 785 : s == 2 ? 197 : 50; }
DEV int selH(int s)     { return s == 0 ? 56 : s == 1 ? 28 : s == 2 ? 14 : 7; }
DEV int selRO(int s)    { return s == 0 ? 0 : s == 1 ? 25096 : s == 2 ? 31376 : 32952; }
DEV size_t selKPB(int s){ return s == 0 ? 0ull : s == 1 ? 6553600ull : s == 2 ? 8650752ull : 9175040ull; }
DEV size_t selVPB(int s){ return s == 0 ? 0ull : s == 1 ? 7340032ull : s == 2 ? 11010048ull : 12845056ull; }
DEV int selNC(int s)    { return s == 0 ? 32 : s == 1 ? 8 : s == 2 ? 2 : 1; }
DEV int selNCB(int s)   { return s == 0 ? 0 : s == 1 ? 2048 : s == 2 ? 2560 : 2688; }

DEV void sbn(int row, int s, int& b, int& n) {
  int l = row - selPB(s);
  if (s == 0)      { b = l / 3200; n = l - b * 3200; }
  else if (s == 1) { b = l >> 10; n = l & 1023; }
  else if (s == 2) { b = l >> 8;  n = l & 255; }
  else             { b = l >> 7;  n = l & 127; }
}

DEV int xcd_swizzle(int orig, int nblk) {
  int q = nblk >> 3, r = nblk & 7;
  int xcd = orig & 7, lin = orig >> 3;
  return (xcd < r ? xcd * (q + 1) : r * (q + 1) + (xcd - r) * q) + lin;
}

// ---------------- merged prep: x1 copy + weight cvt + cpe weight transpose ----------------
__global__ void prep_all(const float4* __restrict__ x1, float4* __restrict__ outx1, int n4,
                         const float* __restrict__ qkv_w, const float* __restrict__ proj_w,
                         const float* __restrict__ fc1_w, const float* __restrict__ fc2_w,
                         u16* __restrict__ WQ, u16* __restrict__ WP,
                         u16* __restrict__ W1, u16* __restrict__ W2,
                         const float* __restrict__ cpe_w, float* __restrict__ WT) {
  int bid = blockIdx.x, t = threadIdx.x;
  if (bid < 8192) {
    for (int i = bid * 256 + t; i < n4; i += 8192 * 256) outx1[i] = x1[i];
  } else if (bid < 14336) {
    int i = (bid - 8192) * 256 + t;
    if (i < 786432) WQ[i] = f2bf(qkv_w[i]);
    else if (i < 1048576) WP[i - 786432] = f2bf(proj_w[i - 786432]);
    else if (i < 1310720) W1[i - 1048576] = f2bf(fc1_w[i - 1048576]);
    else W2[i - 1310720] = f2bf(fc2_w[i - 1310720]);
  } else {
    int b9 = bid - 14336;
    int i = b9 / 9;
    int e = (b9 % 9) * 256 + t;
    if (e < 2304) {
      int c = e / 9, k = e % 9;
      WT[i * 2304 + k * 256 + c] = cpe_w[i * 2304 + c * 9 + k];
    }
  }
}

// ---------------- fused CPE + LN1 (wave per padded row) ----------------
__global__ void cpe_ln_all(const float* __restrict__ x2, const float* __restrict__ x3,
                           const float* __restrict__ x4, const float* __restrict__ x5,
                           const float* __restrict__ WT, const float* __restrict__ cpe_b,
                           const float* __restrict__ n1g, const float* __restrict__ n1b,
                           float* __restrict__ XI, u16* __restrict__ T1) {
  int wid = threadIdx.x >> 6, lane = threadIdx.x & 63;
  int row = blockIdx.x * 4 + wid;
  if (row >= MP) return;
  int s = rs_s(row);
  int b, n; sbn(row, s, b, n);
  int N = selN(s), H = selH(s);
  int c4 = lane * 4;
  float4 v = make_float4(0.f, 0.f, 0.f, 0.f);
  if (n < N) {
    const float* x = s == 0 ? x2 : s == 1 ? x3 : s == 2 ? x4 : x5;
    v = *(const float4*)(x + ((size_t)b * N + n) * 256 + c4);
    if (n > 0) {
      int p = n - 1, h0 = p / H, w0 = p % H;
      float4 acc = *(const float4*)(cpe_b + s * 256 + c4);
      const float* wT = WT + s * 2304;
      #pragma unroll
      for (int kh = 0; kh < 3; ++kh) {
        int hh = h0 + kh - 1;
        if (hh < 0 || hh >= H) continue;
        #pragma unroll
        for (int kw = 0; kw < 3; ++kw) {
          int ww = w0 + kw - 1;
          if (ww < 0 || ww >= H) continue;
          float4 t = *(const float4*)(x + ((size_t)b * N + 1 + hh * H + ww) * 256 + c4);
          float4 wv = *(const float4*)(wT + (kh * 3 + kw) * 256 + c4);
          acc.x += t.x * wv.x; acc.y += t.y * wv.y;
          acc.z += t.z * wv.z; acc.w += t.w * wv.w;
        }
      }
      v.x += acc.x; v.y += acc.y; v.z += acc.z; v.w += acc.w;
    }
  }
  *(float4*)(XI + (size_t)row * 256 + c4) = v;
  float sm = v.x + v.y + v.z + v.w;
  #pragma unroll
  for (int off = 32; off; off >>= 1) sm += __shfl_down(sm, off);
  sm = __shfl(sm, 0);
  float mu = sm * (1.0f / 256.0f);
  float dx = v.x - mu, dy = v.y - mu, dz = v.z - mu, dw = v.w - mu;
  float q = dx * dx + dy * dy + dz * dz + dw * dw;
  #pragma unroll
  for (int off = 32; off; off >>= 1) q += __shfl_down(q, off);
  q = __shfl(q, 0);
  float rs = rsqrtf(q * (1.0f / 256.0f) + 1e-5f);
  float4 gg = *(const float4*)(n1g + s * 256 + c4);
  float4 bb = *(const float4*)(n1b + s * 256 + c4);
  u16x4s o;
  o.x = f2bf(dx * rs * gg.x + bb.x);
  o.y = f2bf(dy * rs * gg.y + bb.y);
  o.z = f2bf(dz * rs * gg.z + bb.z);
  o.w = f2bf(dw * rs * gg.w + bb.w);
  *(u16x4s*)(T1 + (size_t)row * 256 + c4) = o;
}

// ---------------- GEMM: BK=32, 3-buffer depth-2 pipeline, counted vmcnt ----------------
DEV void stage32(const u16* __restrict__ A, const u16* __restrict__ W,
                 u16* dst, int bm, int bn, int K, int k0) {
  int t = threadIdx.x, wv = t >> 6;
  u16* aD = dst;
  u16* bD = dst + 4096;
  #pragma unroll
  for (int iss = 0; iss < 2; ++iss) {
    int sI = iss * 256 + t;
    int row = sI >> 2, g = sI & 3;
    int gel = ((g ^ (row & 3)) << 3);
    __builtin_amdgcn_global_load_lds(
        (const AS1 void*)(A + (size_t)(bm + row) * K + k0 + gel),
        (AS3 void*)(aD + (size_t)(iss * 256 + wv * 64) * 8), 16, 0, 0);
    __builtin_amdgcn_global_load_lds(
        (const AS1 void*)(W + (size_t)(bn + row) * K + k0 + gel),
        (AS3 void*)(bD + (size_t)(iss * 256 + wv * 64) * 8), 16, 0, 0);
  }
}

DEV void mainloop(const u16* __restrict__ A, const u16* __restrict__ W, int K,
                  int bm, int bn, u16* lds, f32x4 (&acc)[4][4]) {
  int t = threadIdx.x, lane = t & 63, wv = t >> 6;
  int wr = wv >> 1, wc = wv & 1;
  const int nt = K >> 5;
  stage32(A, W, lds, bm, bn, K, 0);
  stage32(A, W, lds + 8192, bm, bn, K, 32);
  int buf = 0;
  for (int tt = 0; tt < nt; ++tt) {
    if (tt + 1 < nt) asm volatile("s_waitcnt vmcnt(4)" ::: "memory");
    else             asm volatile("s_waitcnt vmcnt(0)" ::: "memory");
    __builtin_amdgcn_s_barrier();
    asm volatile("" ::: "memory");
    if (tt + 2 < nt) {
      int nb = buf + 2; if (nb >= 3) nb -= 3;
      stage32(A, W, lds + nb * 8192, bm, bn, K, (tt + 2) << 5);
    }
    const u16* aS = lds + buf * 8192;
    const u16* bS = aS + 4096;
    bf16x8 af[4], bfr[4];
    #pragma unroll
    for (int m = 0; m < 4; ++m) {
      int row = wr * 64 + m * 16 + (lane & 15);
      int sg = (lane >> 4) ^ (row & 3);
      af[m] = *(const bf16x8*)(aS + row * 32 + sg * 8);
    }
    #pragma unroll
    for (int n = 0; n < 4; ++n) {
      int row = wc * 64 + n * 16 + (lane & 15);
      int sg = (lane >> 4) ^ (row & 3);
      bfr[n] = *(const bf16x8*)(bS + row * 32 + sg * 8);
    }
    #pragma unroll
    for (int m = 0; m < 4; ++m)
      #pragma unroll
      for (int n = 0; n < 4; ++n)
        acc[m][n] = __builtin_amdgcn_mfma_f32_16x16x32_bf16(af[m], bfr[n], acc[m][n], 0, 0, 0);
    buf += 1; if (buf >= 3) buf -= 3;
  }
}

DEV void epi_dump(const f32x4 (&acc)[4][4], int pass, float* eps) {
  int t = threadIdx.x, lane = t & 63, wv = t >> 6;
  int wr = wv >> 1, wc = wv & 1;
  if (wr != (pass >> 1)) return;
  #pragma unroll
  for (int mh = 0; mh < 2; ++mh) {
    int m = (pass & 1) * 2 + mh;
    #pragma unroll
    for (int n = 0; n < 4; ++n) {
      int col = wc * 64 + n * 16 + (lane & 15);
      #pragma unroll
      for (int rg = 0; rg < 4; ++rg)
        eps[(mh * 16 + ((lane >> 4) << 2) + rg) * 132 + col] = acc[m][n][rg];
    }
  }
}

template <bool GELU, bool BF16>
DEV void epi_rowmajor(const float* eps, int pass, void* outp, const float* bias,
                      int bm, int bn, int Nout) {
  int t = threadIdx.x;
  int lr = t >> 3, cb = (t & 7) * 4;
  int gr = bm + pass * 32 + lr;
  #pragma unroll
  for (int j = 0; j < 4; ++j) {
    int col = cb + j * 32;
    float4 f = *(const float4*)(eps + lr * 132 + col);
    int gc = bn + col;
    if (bias) {
      float4 bv = *(const float4*)(bias + gc);
      f.x += bv.x; f.y += bv.y; f.z += bv.z; f.w += bv.w;
    }
    if (GELU) {
      f.x /= (1.0f + __expf(-1.702f * f.x));
      f.y /= (1.0f + __expf(-1.702f * f.y));
      f.z /= (1.0f + __expf(-1.702f * f.z));
      f.w /= (1.0f + __expf(-1.702f * f.w));
    }
    if (BF16) {
      u16x4s p;
      p.x = f2bf(f.x); p.y = f2bf(f.y); p.z = f2bf(f.z); p.w = f2bf(f.w);
      *(u16x4s*)((u16*)outp + (size_t)gr * Nout + gc) = p;
    } else {
      *(float4*)((float*)outp + (size_t)gr * Nout + gc) = f;
    }
  }
}

// ---------------- standard GEMM (fc1) ----------------
template <bool GELU, bool BF16>
__launch_bounds__(256, 3)
__global__ void gemm_std(const u16* __restrict__ A, const u16* __restrict__ W,
                         const float* __restrict__ bias, void* __restrict__ outp,
                         int K, int Nout, int nnt) {
  __shared__ __align__(16) u16 lds[24576];
  int wg = xcd_swizzle(blockIdx.x, gridDim.x);
  int bm = (wg / nnt) << 7, bn = (wg % nnt) << 7;
  f32x4 acc[4][4] = {};
  mainloop(A, W, K, bm, bn, lds, acc);
  float* eps = (float*)lds;
  #pragma unroll
  for (int pass = 0; pass < 4; ++pass) {
    __syncthreads();
    epi_dump(acc, pass, eps);
    __syncthreads();
    epi_rowmajor<GELU, BF16>(eps, pass, outp, bias, bm, bn, Nout);
  }
}

// ---------------- qkv GEMM: q row-major bf16; k,v planar-transposed ----------------
__launch_bounds__(256, 3)
__global__ void qkv_gemm(const u16* __restrict__ A, const u16* __restrict__ WQ,
                         u16* __restrict__ Q16, u16* __restrict__ KP,
                         u16* __restrict__ VP) {
  __shared__ __align__(16) u16 lds[24576];
  int wg = xcd_swizzle(blockIdx.x, gridDim.x);
  int mt = wg / 6, ct = wg % 6;
  int bm = mt << 7, bn = ct << 7;
  int s = rs_s(bm);
  f32x4 acc[4][4] = {};
  mainloop(A, WQ + (size_t)s * 196608, 256, bm, bn, lds, acc);
  float* eps = (float*)lds;
  int b, nb; sbn(bm, s, b, nb);
  int NPAD = selNPAD(s);
  #pragma unroll
  for (int pass = 0; pass < 4; ++pass) {
    __syncthreads();
    epi_dump(acc, pass, eps);
    __syncthreads();
    if (ct < 2) {
      epi_rowmajor<false, true>(eps, pass, Q16, nullptr, bm, bn, 256);
    } else {
      int t = threadIdx.x;
      int c = t >> 1, half = t & 1;
      bool isK = (ct < 4);
      int cg = bn - (isK ? 256 : 512) + c;
      int n0 = nb + pass * 32 + half * 16;
      float vals[16];
      #pragma unroll
      for (int r = 0; r < 16; ++r) vals[r] = eps[(half * 16 + r) * 132 + c];
      U16x8 p0, p1;
      #pragma unroll
      for (int e = 0; e < 8; ++e) { p0.d[e] = f2bf(vals[e]); p1.d[e] = f2bf(vals[8 + e]); }
      u16* pbase = (isK ? KP : VP) + selKPB(s) + (size_t)(b * 256 + cg) * NPAD + n0;
      *(U16x8*)pbase = p0;
      *(U16x8*)(pbase + 8) = p1;
    }
  }
}

// ---------------- proj GEMM (bf16 out into CC16) ----------------
__launch_bounds__(256, 3)
__global__ void proj_gemm(const u16* __restrict__ A, const u16* __restrict__ WP,
                          const float* __restrict__ proj_b, u16* __restrict__ CC16) {
  __shared__ __align__(16) u16 lds[24576];
  int wg = xcd_swizzle(blockIdx.x, gridDim.x);
  int bm = (wg >> 1) << 7, bn = (wg & 1) << 7;
  int s = rs_s(bm);
  f32x4 acc[4][4] = {};
  mainloop(A, WP + (size_t)s * 65536, 256, bm, bn, lds, acc);
  float* eps = (float*)lds;
  #pragma unroll
  for (int pass = 0; pass < 4; ++pass) {
    __syncthreads();
    epi_dump(acc, pass, eps);
    __syncthreads();
    epi_rowmajor<false, true>(eps, pass, CC16, proj_b + s * 256, bm, bn, 256);
  }
}

// ---------------- fc2 GEMM: +bias +XI residual, remapped f32 out ----------------
__launch_bounds__(256, 3)
__global__ void fc2_gemm(const u16* __restrict__ A, const u16* __restrict__ W2,
                         const float* __restrict__ fc2_b, const float* __restrict__ XI,
                         float* __restrict__ out) {
  __shared__ __align__(16) u16 lds[24576];
  int wg = xcd_swizzle(blockIdx.x, gridDim.x);
  int bm = (wg >> 1) << 7, bn = (wg & 1) << 7;
  f32x4 acc[4][4] = {};
  mainloop(A, W2, 1024, bm, bn, lds, acc);
  float* eps = (float*)lds;
  int s = rs_s(bm);
  int b, nb; sbn(bm, s, b, nb);
  int N = selN(s), RO = selRO(s);
  #pragma unroll
  for (int pass = 0; pass < 4; ++pass) {
    __syncthreads();
    epi_dump(acc, pass, eps);
    __syncthreads();
    int t = threadIdx.x;
    int lr = t >> 3, cb = (t & 7) * 4;
    int n = nb + pass * 32 + lr;
    if (n >= N) continue;
    int prow = bm + pass * 32 + lr;
    size_t orow = (size_t)RO + (size_t)b * N + n;
    #pragma unroll
    for (int j = 0; j < 4; ++j) {
      int col = cb + j * 32;
      float4 f = *(const float4*)(eps + lr * 132 + col);
      int gc = bn + col;
      float4 bv = *(const float4*)(fc2_b + gc);
      float4 rv = *(const float4*)(XI + (size_t)prow * 256 + gc);
      f.x += bv.x + rv.x; f.y += bv.y + rv.y;
      f.z += bv.z + rv.z; f.w += bv.w + rv.w;
      *(float4*)(out + OUTOFF0 + orow * 256 + gc) = f;
    }
  }
}

// ---------------- merged: padded V-image fill + k softmax stats ----------------
DEV void vimg_one(const u16* __restrict__ VP, u16* __restrict__ VPI, int plane) {
  int s = plane >> 11;
  int pc = plane & 2047;
  int H = selH(s), NPAD = selNPAD(s);
  const u16* vp = VP + selKPB(s) + (size_t)pc * NPAD;
  u16* vi = VPI + selVPB(s) + (size_t)pc * (H * 64);
  int tot = H * 64;
  for (int e = threadIdx.x; e < tot; e += 256) {
    int h = e >> 6, w = e & 63;
    vi[e] = (w < H) ? vp[1 + h * H + w] : (u16)0;
  }
}

DEV void ksm_one(const u16* __restrict__ KP, float* __restrict__ mx, float* __restrict__ se,
                 int xblk, int b, int s) {
  int N = selN(s), NPAD = selNPAD(s);
  int wv = threadIdx.x >> 6, lane = threadIdx.x & 63;
  int cg = xblk * 4 + wv;
  const u16* kp = KP + selKPB(s) + (size_t)(b * 256 + cg) * NPAD;
  float m = -1e30f, sm = 0.f;
  for (int n = lane; n < N; n += 64) {
    float v = bf2f(kp[n]);
    float nm = fmaxf(m, v);
    sm = sm * __expf(m - nm) + __expf(v - nm);
    m = nm;
  }
  #pragma unroll
  for (int off = 1; off < 64; off <<= 1) {
    float mo = __shfl_xor(m, off), so = __shfl_xor(sm, off);
    float nm = fmaxf(m, mo);
    sm = sm * __expf(m - nm) + so * __expf(mo - nm);
    m = nm;
  }
  if (lane == 0) { mx[s * 2048 + b * 256 + cg] = m; se[s * 2048 + b * 256 + cg] = sm; }
}

__global__ void vksm_pack(const u16* __restrict__ VP, u16* __restrict__ VPI,
                          const u16* __restrict__ KP, float* __restrict__ mx,
                          float* __restrict__ se) {
  int bid = blockIdx.x;
  if (bid < 8192) {
    vimg_one(VP, VPI, bid);
  } else {
    int r = bid - 8192;           // 2048 = 64 x 8 x 4
    ksm_one(KP, mx, se, r & 63, (r >> 6) & 7, r >> 9);
  }
}

// ---------------- kv partials ----------------
__launch_bounds__(1024)
__global__ void kv_partial_all(const u16* __restrict__ KP, const u16* __restrict__ VP,
                               const float* __restrict__ mx, float* __restrict__ part) {
  __shared__ float kl[32][65];
  __shared__ float vl[32][65];
  int blk = blockIdx.x;
  int s = (blk >= selNCB(1)) + (blk >= selNCB(2)) + (blk >= selNCB(3));
  int local = blk - selNCB(s);
  int NC = selNC(s);
  int chunk = local % NC;
  int bh = local / NC;
  int b = bh >> 3, h = bh & 7;
  int N = selN(s), NPAD = selNPAD(s);
  int chunkrows = (N + NC - 1) / NC;
  const u16* kpb = KP + selKPB(s);
  const u16* vpb = VP + selKPB(s);
  int t = threadIdx.x;
  int i = t >> 5, j = t & 31;
  float acc = 0.f;
  int n0s = chunk * chunkrows, n1s = min(N, n0s + chunkrows);
  for (int n0 = n0s; n0 < n1s; n0 += 64) {
    #pragma unroll
    for (int e = t; e < 2048; e += 1024) {
      int c = e >> 6, nn = e & 63;
      int n = n0 + nn;
      bool ok = (n < n1s);
      kl[c][nn] = ok ? bf2f(kpb[(size_t)(b * 256 + h * 32 + c) * NPAD + n]) : -1e30f;
      vl[c][nn] = ok ? bf2f(vpb[(size_t)(b * 256 + h * 32 + c) * NPAD + n]) : 0.f;
    }
    __syncthreads();
    #pragma unroll
    for (int e = t; e < 2048; e += 1024) {
      int c = e >> 6, nn = e & 63;
      kl[c][nn] = __expf(kl[c][nn] - mx[s * 2048 + b * 256 + h * 32 + c]);
    }
    __syncthreads();
    #pragma unroll
    for (int nn = 0; nn < 64; ++nn) acc += kl[i][nn] * vl[j][nn];
    __syncthreads();
  }
  part[(size_t)blk * 1024 + t] = acc;
}

// ---------------- merged: CRPE (3/5/7) + kv reduce ----------------
template <int KS, int C0>
DEV void crpe_one(const u16* __restrict__ VPI, const float* __restrict__ w,
                  const float* __restrict__ bias, u16* __restrict__ CVPI, int CS,
                  int c, int b, int sub) {
  constexpr int pad = KS / 2;
  int s = (sub >= 2) + (sub >= 3) + (sub >= 4);
  int z = sub - (s == 0 ? 0 : s + 1);
  int RS = (s == 0) ? 2 : 1;
  int H = selH(s);
  int G = (H + 7) >> 3;
  int hpb = (H + RS - 1) / RS;
  int h0b = z * hpb;
  int h1b = min(H, h0b + hpb);
  size_t plane = selVPB(s) + (size_t)(b * 256 + C0 + c) * (size_t)(H * 64);
  const u16* vp = VPI + plane;
  u16* op = CVPI + plane;
  float wreg[KS * KS];
  #pragma unroll
  for (int e = 0; e < KS * KS; ++e) wreg[e] = w[(s * CS + c) * KS * KS + e];
  float bb = bias[s * CS + c];
  int ntask = (h1b - h0b) * G;
  for (int task = threadIdx.x; task < ntask; task += 256) {
    int g = task % G;
    int h = h0b + task / G;
    int w0 = g << 3;
    float o[8];
    #pragma unroll
    for (int e = 0; e < 8; ++e) o[e] = bb;
    #pragma unroll
    for (int kh = 0; kh < KS; ++kh) {
      int hh = h + kh - pad;
      if (hh < 0 || hh >= H) continue;
      const u16* rowp = vp + hh * 64;
      U16x8 ch0 = {}, ch1, ch2;
      if (w0 >= 8) ch0 = *(const U16x8*)(rowp + w0 - 8);
      ch1 = *(const U16x8*)(rowp + w0);
      ch2 = *(const U16x8*)(rowp + w0 + 8);
      float tv[24];
      #pragma unroll
      for (int j2 = 8 - pad; j2 <= 15 + pad; ++j2) {
        u16 raw = (j2 < 8) ? ch0.d[j2] : (j2 < 16 ? ch1.d[j2 - 8] : ch2.d[j2 - 16]);
        tv[j2] = bf2f(raw);
      }
      #pragma unroll
      for (int kw = 0; kw < KS; ++kw) {
        float wv = wreg[kh * KS + kw];
        #pragma unroll
        for (int e = 0; e < 8; ++e) o[e] += tv[8 + e + kw - pad] * wv;
      }
    }
    U16x8 pk;
    #pragma unroll
    for (int e = 0; e < 8; ++e) pk.d[e] = f2bf(o[e]);
    *(U16x8*)(op + h * 64 + w0) = pk;
  }
}

DEV void kv_reduce_one(const float* __restrict__ part, const float* __restrict__ se,
                       u16* __restrict__ kvh, int bh, int s) {
  int NC = selNC(s), base = selNCB(s);
  int b = bh >> 3, h = bh & 7;
  for (int tt = threadIdx.x; tt < 1024; tt += 256) {
    int i = tt >> 5;
    float sm = 0.f;
    for (int c = 0; c < NC; ++c) sm += part[(size_t)(base + bh * NC + c) * 1024 + tt];
    kvh[(size_t)s * 65536 + bh * 1024 + tt] = f2bf(sm / se[s * 2048 + b * 256 + h * 32 + i]);
  }
}

__global__ void crpe_pack(const u16* __restrict__ VPI,
                          const float* __restrict__ w3, const float* __restrict__ b3,
                          const float* __restrict__ w5, const float* __restrict__ b5,
                          const float* __restrict__ w7, const float* __restrict__ b7,
                          u16* __restrict__ CVPI,
                          const float* __restrict__ PRT, const float* __restrict__ SE,
                          u16* __restrict__ KVH) {
  int bid = blockIdx.x;
  if (bid < 2560) {                         // 64 x 8 x 5
    crpe_one<3, 0>(VPI, w3, b3, CVPI, 64, bid & 63, (bid >> 6) & 7, bid >> 9);
  } else if (bid < 6400) {                  // 96 x 8 x 5
    int r = bid - 2560;
    crpe_one<5, 64>(VPI, w5, b5, CVPI, 96, r % 96, (r / 96) & 7, r / 768);
  } else if (bid < 10240) {
    int r = bid - 6400;
    crpe_one<7, 160>(VPI, w7, b7, CVPI, 96, r % 96, (r / 96) & 7, r / 768);
  } else {                                   // 256 = 64 bh x 4 s
    int r = bid - 10240;
    kv_reduce_one(PRT, SE, KVH, r & 63, r >> 6);
  }
}

// ---------------- att: 32 tokens/block, bf16 LDS, kv column in registers ----------------
__launch_bounds__(256, 3)
__global__ void att_all(const u16* __restrict__ Q16, const u16* __restrict__ CVPI,
                        const u16* __restrict__ kvh, u16* __restrict__ attp) {
  int s = blockIdx.z, b = blockIdx.y;
  int N = selN(s), H = selH(s);
  int n0 = blockIdx.x * 32;
  if (n0 >= N) return;
  __shared__ u16 kvl[8192];
  __shared__ u16 ql[32][256];
  __shared__ u16 cl[32][256];
  int t = threadIdx.x;
  int hw64 = H * 64;
  size_t rowbase = (size_t)selPB(s) + (size_t)b * selNPAD(s);
  const u16* cvb = CVPI + selVPB(s);
  const u16* kvsrc = kvh + (size_t)s * 65536 + (size_t)b * 8192;
  for (int e = t; e < 1024; e += 256)
    *(U16x8*)(kvl + e * 8) = *(const U16x8*)(kvsrc + e * 8);
  for (int e = t; e < 1024; e += 256)
    *(U16x8*)(&ql[0][0] + e * 8) = *(const U16x8*)(Q16 + (rowbase + n0) * 256 + e * 8);
  for (int e = t; e < 8192; e += 256) {
    int c = e >> 5, nn = e & 31;
    int n = n0 + nn;
    u16 v = 0;
    if (n >= 1 && n < N) {
      int p = n - 1;
      v = cvb[(size_t)(b * 256 + c) * hw64 + (p / H) * 64 + (p % H)];
    }
    cl[nn][c] = v;
  }
  __syncthreads();
  int h = t >> 5, j = t & 31;
  float kvr[32];
  #pragma unroll
  for (int k = 0; k < 32; ++k) kvr[k] = bf2f(kvl[(h * 32 + k) * 32 + j]);
  for (int nn = 0; nn < 32; ++nn) {
    int n = n0 + nn;
    if (n >= N) break;
    float fa = 0.f;
    const U16x8* qp = (const U16x8*)(&ql[nn][h * 32]);
    #pragma unroll
    for (int seg = 0; seg < 4; ++seg) {
      U16x8 qq = qp[seg];
      #pragma unroll
      for (int e = 0; e < 8; ++e) fa += bf2f(qq.d[e]) * kvr[seg * 8 + e];
    }
    float v = 0.17677669529663687f * fa + bf2f(ql[nn][t]) * bf2f(cl[nn][t]);
    attp[(rowbase + n) * 256 + t] = f2bf(v);
  }
}

// ---------------- fused cross-scale combine + LN2 (CC in bf16) ----------------
DEV float4 ld4h(const u16* p) {
  u16x4s r = *(const u16x4s*)p;
  return make_float4(bf2f(r.x), bf2f(r.y), bf2f(r.z), bf2f(r.w));
}

DEV float4 bs4h(const u16* __restrict__ base, int Hs, int oh, int ow, int Hi, int c4) {
  float scale = (float)Hs / (float)Hi;
  float sy = (oh + 0.5f) * scale - 0.5f;
  float sx = (ow + 0.5f) * scale - 0.5f;
  float fy0 = floorf(sy), fx0 = floorf(sx);
  float fy = sy - fy0, fx = sx - fx0;
  int y0 = (int)fy0, x0 = (int)fx0;
  int y0c = min(max(y0, 0), Hs - 1), y1c = min(max(y0 + 1, 0), Hs - 1);
  int x0c = min(max(x0, 0), Hs - 1), x1c = min(max(x0 + 1, 0), Hs - 1);
  const u16* ib = base + 256 + c4;
  float4 v00 = ld4h(ib + (size_t)(y0c * Hs + x0c) * 256);
  float4 v01 = ld4h(ib + (size_t)(y0c * Hs + x1c) * 256);
  float4 v10 = ld4h(ib + (size_t)(y1c * Hs + x0c) * 256);
  float4 v11 = ld4h(ib + (size_t)(y1c * Hs + x1c) * 256);
  float w00 = (1.f - fy) * (1.f - fx), w01 = (1.f - fy) * fx;
  float w10 = fy * (1.f - fx), w11 = fy * fx;
  float4 r;
  r.x = w00 * v00.x + w01 * v01.x + w10 * v10.x + w11 * v11.x;
  r.y = w00 * v00.y + w01 * v01.y + w10 * v10.y + w11 * v11.y;
  r.z = w00 * v00.z + w01 * v01.z + w10 * v10.z + w11 * v11.z;
  r.w = w00 * v00.w + w01 * v01.w + w10 * v10.w + w11 * v11.w;
  return r;
}

__global__ void combine_ln_all(float* __restrict__ XI, const u16* __restrict__ CC16,
                               const float* __restrict__ n2g, const float* __restrict__ n2b,
                               u16* __restrict__ T1) {
  int wid = threadIdx.x >> 6, lane = threadIdx.x & 63;
  int row = blockIdx.x * 4 + wid;
  if (row >= MP) return;
  int s = rs_s(row);
  int b, n; sbn(row, s, b, n);
  int N = selN(s), Hi = selH(s);
  int c4 = lane * 4;
  float4 v;
  if (n < N) {
    float4 add = ld4h(CC16 + (size_t)row * 256 + c4);
    int sa = s == 0 ? 1 : s == 1 ? 2 : s == 2 ? 3 : 2;
    int sb_ = s == 0 ? 2 : 0;
    const u16* baseA = CC16 + ((size_t)selPB(sa) + (size_t)b * selNPAD(sa)) * 256;
    const u16* baseB = CC16 + ((size_t)selPB(sb_) + (size_t)b * selNPAD(sb_)) * 256;
    if (n == 0) {
      float4 a = ld4h(baseA + c4);
      float4 bb2 = ld4h(baseB + c4);
      add.x += a.x + bb2.x; add.y += a.y + bb2.y;
      add.z += a.z + bb2.z; add.w += a.w + bb2.w;
    } else {
      int p = n - 1, oh = p / Hi, ow = p % Hi;
      float4 a = bs4h(baseA, selH(sa), oh, ow, Hi, c4);
      float4 bb2 = bs4h(baseB, selH(sb_), oh, ow, Hi, c4);
      add.x += a.x + bb2.x; add.y += a.y + bb2.y;
      add.z += a.z + bb2.z; add.w += a.w + bb2.w;
    }
    float* xp = XI + (size_t)row * 256 + c4;
    v = *(const float4*)xp;
    v.x += add.x; v.y += add.y; v.z += add.z; v.w += add.w;
    *(float4*)xp = v;
  } else {
    v = make_float4(0.f, 0.f, 0.f, 0.f);
  }
  float sm = v.x + v.y + v.z + v.w;
  #pragma unroll
  for (int off = 32; off; off >>= 1) sm += __shfl_down(sm, off);
  sm = __shfl(sm, 0);
  float mu = sm * (1.0f / 256.0f);
  float dx = v.x - mu, dy = v.y - mu, dz = v.z - mu, dw = v.w - mu;
  float q = dx * dx + dy * dy + dz * dz + dw * dw;
  #pragma unroll
  for (int off = 32; off; off >>= 1) q += __shfl_down(q, off);
  q = __shfl(q, 0);
  float rs = rsqrtf(q * (1.0f / 256.0f) + 1e-5f);
  float4 gg = *(const float4*)(n2g + s * 256 + c4);
  float4 bb = *(const float4*)(n2b + s * 256 + c4);
  u16x4s o;
  o.x = f2bf(dx * rs * gg.x + bb.x);
  o.y = f2bf(dy * rs * gg.y + bb.y);
  o.z = f2bf(dz * rs * gg.z + bb.z);
  o.w = f2bf(dw * rs * gg.w + bb.w);
  *(u16x4s*)(T1 + (size_t)row * 256 + c4) = o;
}

// ---------------- host ----------------
extern "C" void kernel_launch(void* const* d_in, const int* in_sizes, int n_in,
                              void* d_out, int out_size, void* d_ws, size_t ws_size,
                              hipStream_t stream) {
  const float* x1 = (const float*)d_in[0];
  const float* x2 = (const float*)d_in[1];
  const float* x3 = (const float*)d_in[2];
  const float* x4 = (const float*)d_in[3];
  const float* x5 = (const float*)d_in[4];
  const float* cpe_w  = (const float*)d_in[5];
  const float* cpe_b  = (const float*)d_in[6];
  const float* n1_g   = (const float*)d_in[7];
  const float* n1_b   = (const float*)d_in[8];
  const float* qkv_w  = (const float*)d_in[9];
  const float* proj_w = (const float*)d_in[10];
  const float* proj_b = (const float*)d_in[11];
  const float* crpe_w3 = (const float*)d_in[12];
  const float* crpe_b3 = (const float*)d_in[13];
  const float* crpe_w5 = (const float*)d_in[14];
  const float* crpe_b5 = (const float*)d_in[15];
  const float* crpe_w7 = (const float*)d_in[16];
  const float* crpe_b7 = (const float*)d_in[17];
  const float* n2_g   = (const float*)d_in[18];
  const float* n2_b   = (const float*)d_in[19];
  const float* fc1_w  = (const float*)d_in[20];
  const float* fc1_b  = (const float*)d_in[21];
  const float* fc2_w  = (const float*)d_in[22];
  const float* fc2_b  = (const float*)d_in[23];

  float* ws = (float*)d_ws;
  float* XI   = ws;
  u16*   CC16 = (u16*)(XI + 9437184);
  u16*   T1   = CC16 + 9437184;
  float* REG  = (float*)(T1 + 9437184);
  u16*   Q16  = (u16*)REG;
  u16*   KP   = Q16 + 9437184;
  u16*   VP   = KP + 9437184;
  u16*   VPI  = VP + 9437184;
  u16*   CVPI = VPI + 13762560;
  float* PRT  = (float*)CVPI;
  u16*   T2   = (u16*)REG;
  float* MX   = (float*)(CVPI + 13762560);
  float* SE   = MX + 8192;
  u16*   KVH  = (u16*)(SE + 8192);
  u16*   WQ   = KVH + 262144;
  u16*   WP   = WQ + 786432;
  u16*   W1   = WP + 262144;
  u16*   W2   = W1 + 262144;
  float* WT   = (float*)(W2 + 262144);

  float* out = (float*)d_out;

  // prep: x1 copy + weight cvt + cpe weight transpose (one dispatch)
  prep_all<<<14372, 256, 0, stream>>>((const float4*)x1, (float4*)out, 25692160 / 4,
                                      qkv_w, proj_w, fc1_w, fc2_w, WQ, WP, W1, W2,
                                      cpe_w, WT);

  // phase 1a: fused CPE + LN1
  cpe_ln_all<<<MP / 4, 256, 0, stream>>>(x2, x3, x4, x5, WT, cpe_b, n1_g, n1_b, XI, T1);

  // phase 1b: qkv GEMM (q row-major, k/v planar)
  qkv_gemm<<<288 * 6, 256, 0, stream>>>(T1, WQ, Q16, KP, VP);

  // phase 1c: attention mid-section (merged dispatches)
  vksm_pack<<<10240, 256, 0, stream>>>(VP, VPI, KP, MX, SE);
  kv_partial_all<<<2752, 1024, 0, stream>>>(KP, VP, MX, PRT);
  crpe_pack<<<10496, 256, 0, stream>>>(VPI, crpe_w3, crpe_b3, crpe_w5, crpe_b5,
                                       crpe_w7, crpe_b7, CVPI, PRT, SE, KVH);
  att_all<<<dim3(99, 8, 4), 256, 0, stream>>>(Q16, CVPI, KVH, T1);

  // phase 1d: proj GEMM (bf16 -> CC16)
  proj_gemm<<<288 * 2, 256, 0, stream>>>(T1, WP, proj_b, CC16);

  // phase 2: fused combine + LN2 (bf16 CC)
  combine_ln_all<<<MP / 4, 256, 0, stream>>>(XI, CC16, n2_g, n2_b, T1);

  // phase 3: MLP
  gemm_std<true, true><<<288 * 8, 256, 0, stream>>>(T1, W1, fc1_b, (void*)T2, 256, 1024, 8);
  fc2_gemm<<<288 * 2, 256, 0, stream>>>(T2, W2, fc2_b, XI, out);
}